// Round 1
// baseline (10608.826 us; speedup 1.0000x reference)
//
#include <hip/hip_runtime.h>
#include <hip/hip_bf16.h>

#define B_ 16
#define N_ 358
#define P_ 72
#define D_ 96
#define ND_ 64
#define H_ 4
#define NH_ 4
#define HD_ 24
#define K_ 10
#define BN_ (B_*N_)     /* 5728 */
#define NN_ (N_*N_)     /* 128164 */
#define RPW_ 6          /* ceil(358/64) elements per lane in wave-per-row kernels */
#define NR5 5           /* rows per 32-lane group in attn (16 groups x 5 = 80 padded rows) */

__device__ __forceinline__ float gelu_f(float x){ return 0.5f*x*(1.0f+erff(x*0.7071067811865476f)); }
__device__ __forceinline__ float sigm_f(float x){ return 1.0f/(1.0f+expf(-x)); }

// ---------------------------------------------------------------------------
// Kernel 1: temporal attention + node embedding (one block per (b,n) sequence)
//
// ROUND-7 REDESIGN (occupancy + LDS-vectorization + parallel softmax):
//  - 512 threads, 16 half-wave groups x 5 rows (72 rows padded to 80 with
//    zero rows; pad rows flow through but are excluded from reductions/IO).
//  - accumulators 4x[3][5]=60 VGPR (vs old 4x[3][9]=108) -> peak liveness
//    ~115, so __launch_bounds__(512,4) (cap 128 VGPR) fits WITHOUT spill.
//    This is NOT the old scarred case: R4-R6 forced 108-accum tiles into
//    64/128-reg tiers. 2 blocks/CU x 8 waves = 4 waves/SIMD (2x the old 2).
//  - all hot LDS paths are ds_read_b128: X stride 100, Q stride 28,
//    K transposed [24][97], V transposed [24][80], P stride 76, O stride 28.
//  - softmax is in-register per row via width-32 __shfl_xor (no serial
//    72-iter loop, no extra barrier).
//  - 3 barriers per head: [A] stage visible -> scores+softmax+P write ->
//    [B] -> PV (P,Vt -> Obuf) -> [C] -> Oproj(Obuf,wo) + stage(h+1).
//    Obuf is a dedicated region so stage(h+1) never collides with O reads.
//  - LDS ~58.5KB/block; 2 blocks/CU (117KB) — VGPR is the binding resource.
// ---------------------------------------------------------------------------
__global__ __launch_bounds__(512, 4) void attn_kernel(
    const float* __restrict__ patch, const float* __restrict__ pos,
    const float* __restrict__ wq, const float* __restrict__ bq,
    const float* __restrict__ wk, const float* __restrict__ bk,
    const float* __restrict__ wv, const float* __restrict__ bv,
    const float* __restrict__ wo, const float* __restrict__ bo,
    const float* __restrict__ tng, const float* __restrict__ tnb,
    float* __restrict__ node_out, float* __restrict__ meanpr_out)
{
    // pool layout (floats):
    //   phase1 : xs  [80][100]              = [0,8000)
    //   heads  : qh  [80][28]  (Q*rs)       = [0,2240)
    //            khT [24][97]  (K^T)        = [2240,4568)
    //            vhT [24][80]  (V^T)        = [4568,6488)
    //            att [80][76]  (P)          = [6488,12568)
    //            obuf[80][28]  (O = P@V)    = [12568,14808)
    //   epilog : ats [80][100] (attended)   = [0,8000)
    __shared__ __align__(16) float pool[14808];
    __shared__ float rr[80];
    __shared__ float nb[D_];
    __shared__ float st2[2];

    float* const xs   = pool;
    float* const qh   = pool;
    float* const khT  = pool + 2240;
    float* const vhT  = pool + 4568;
    float* const att  = pool + 6488;
    float* const obuf = pool + 12568;
    float* const ats  = pool;

    const int tid = threadIdx.x;
    const int tc  = tid & 31;
    const int tr  = tid >> 5;           // 0..15
    const int rbase = tr * NR5;         // 0,5,...,75
    const int bn  = blockIdx.x;
    const float* pr = patch + (size_t)bn * (P_*D_);

    // mean over P of pr (node_f) -- kept in a register by threads tid<96
    float mpr = 0.f;
    if (tid < D_) {
        for (int p = 0; p < P_; ++p) mpr += pr[p*D_+tid];
        mpr *= (1.0f/P_);
        meanpr_out[(size_t)bn*D_ + tid] = mpr;
    }

    // load X = pr + pos into LDS [80][100]; rows 72..79 and cols 96..99 zero
    for (int e = tid; e < 80*100; e += 512) {
        const int row = e / 100, col = e - row*100;
        xs[e] = (row < P_ && col < D_) ? (pr[row*D_+col] + pos[row*D_+col]) : 0.f;
    }
    __syncthreads();

    // ---- phase 1: Q,K,V = X @ W + b, all heads, accumulated in registers ----
    float aq[3][NR5], ak[3][NR5], av[3][NR5];
    #pragma unroll
    for (int j = 0; j < 3; ++j) {
        const int c = tc + 32*j;
        const float vbq = bq[c], vbk = bk[c], vbv = bv[c];
        #pragma unroll
        for (int i = 0; i < NR5; ++i) { aq[j][i]=vbq; ak[j][i]=vbk; av[j][i]=vbv; }
    }

#define P1_MAT(WP, ACC)                                                      \
        {                                                                    \
            float w4[3][4];                                                  \
            _Pragma("unroll")                                                \
            for (int j = 0; j < 3; ++j) {                                    \
                const int c = tc + 32*j;                                     \
                _Pragma("unroll")                                            \
                for (int kk = 0; kk < 4; ++kk)                               \
                    w4[j][kk] = WP[(k0+kk)*D_ + c];                          \
            }                                                                \
            _Pragma("unroll")                                                \
            for (int j = 0; j < 3; ++j)                                      \
                _Pragma("unroll")                                            \
                for (int i = 0; i < NR5; ++i)                                \
                    ACC[j][i] += xv[i].x*w4[j][0] + xv[i].y*w4[j][1]         \
                               + xv[i].z*w4[j][2] + xv[i].w*w4[j][3];        \
        }

    for (int k0 = 0; k0 < D_; k0 += 4) {
        float4 xv[NR5];
        #pragma unroll
        for (int i = 0; i < NR5; ++i)
            xv[i] = *reinterpret_cast<const float4*>(&xs[(rbase+i)*100 + k0]);
        P1_MAT(wq, aq)
        P1_MAT(wk, ak)
        P1_MAT(wv, av)
    }
    __syncthreads();        // all xs reads done; pool free for head buffers

    const float rs = 0.20412414523193154f;      // 1/sqrt(24)

    // attended accumulators (output of o @ wo + bo), live across heads
    float ao[3][NR5];
    #pragma unroll
    for (int j = 0; j < 3; ++j) {
        const float vbo = bo[tc + 32*j];
        #pragma unroll
        for (int i = 0; i < NR5; ++i) ao[j][i] = vbo;
    }

    // stage head hh's Q (pre-scaled by rs), K^T, V^T slices from registers
    auto stage = [&](int hh) {
        #pragma unroll
        for (int j = 0; j < 3; ++j) {
            const int c = tc + 32*j;
            const int dl = c - HD_*hh;
            if ((unsigned)dl < (unsigned)HD_) {
                #pragma unroll
                for (int i = 0; i < NR5; ++i) {
                    const int row = rbase + i;
                    qh [row*28 + dl] = aq[j][i] * rs;
                    khT[dl*97 + row] = ak[j][i];
                    vhT[dl*80 + row] = av[j][i];
                }
            }
        }
    };

    stage(0);
    __syncthreads();    // A0: head-0 qh/khT/vhT visible

    for (int h = 0; h < NH_; ++h) {
        // ---- scores S = (Q*rs) K^T, rows rbase..+4, cols jn = tc+32*j ----
        float sc[3][NR5];
        #pragma unroll
        for (int j = 0; j < 3; ++j)
            #pragma unroll
            for (int i = 0; i < NR5; ++i) sc[j][i] = 0.f;
        for (int d0 = 0; d0 < HD_; d0 += 4) {
            float4 qv[NR5];
            #pragma unroll
            for (int i = 0; i < NR5; ++i)
                qv[i] = *reinterpret_cast<const float4*>(&qh[(rbase+i)*28 + d0]);
            float kv[3][4];
            #pragma unroll
            for (int j = 0; j < 3; ++j) {
                const int jn = tc + 32*j;           // <=95 < 97: in-bounds; jn>=72 masked below
                #pragma unroll
                for (int kk = 0; kk < 4; ++kk)
                    kv[j][kk] = khT[(d0+kk)*97 + jn];
            }
            #pragma unroll
            for (int j = 0; j < 3; ++j)
                #pragma unroll
                for (int i = 0; i < NR5; ++i)
                    sc[j][i] += qv[i].x*kv[j][0] + qv[i].y*kv[j][1]
                              + qv[i].z*kv[j][2] + qv[i].w*kv[j][3];
        }

        // ---- in-register row softmax (row owned by one 32-lane group) ----
        #pragma unroll
        for (int i = 0; i < NR5; ++i) {
            float m = fmaxf(sc[0][i], sc[1][i]);
            if (tc < 8) m = fmaxf(m, sc[2][i]);         // jn=64+tc valid iff tc<8
            #pragma unroll
            for (int s = 1; s < 32; s <<= 1) m = fmaxf(m, __shfl_xor(m, s, 32));
            const float e0 = expf(sc[0][i]-m);
            const float e1 = expf(sc[1][i]-m);
            const float e2 = (tc < 8) ? expf(sc[2][i]-m) : 0.f;
            float sm = e0 + e1 + e2;
            #pragma unroll
            for (int s = 1; s < 32; s <<= 1) sm += __shfl_xor(sm, s, 32);
            const float inv = 1.0f/sm;
            const int row = rbase + i;
            att[row*76 + tc]      = e0*inv;
            att[row*76 + tc + 32] = e1*inv;
            if (tc < 8) att[row*76 + tc + 64] = e2*inv;
        }
        __syncthreads();    // B: P visible; qh/khT reads done

        // ---- PV: O[row][tc] = sum_j P[row][j] V[j][tc]  (tc < 24) ----
        if (tc < HD_) {
            float ov[NR5];
            #pragma unroll
            for (int i = 0; i < NR5; ++i) ov[i] = 0.f;
            for (int j0 = 0; j0 < P_; j0 += 4) {
                const float4 vv = *reinterpret_cast<const float4*>(&vhT[tc*80 + j0]);
                #pragma unroll
                for (int i = 0; i < NR5; ++i) {
                    const float4 pa = *reinterpret_cast<const float4*>(&att[(rbase+i)*76 + j0]);
                    ov[i] += pa.x*vv.x + pa.y*vv.y + pa.z*vv.z + pa.w*vv.w;
                }
            }
            #pragma unroll
            for (int i = 0; i < NR5; ++i) obuf[(rbase+i)*28 + tc] = ov[i];
        }
        __syncthreads();    // C: O visible; att/vhT reads done

        // ---- Oproj: attended += O @ wo[24h:24h+24, :]  (+ stage next head) ----
        for (int d0 = 0; d0 < HD_; d0 += 4) {
            float4 ov4[NR5];
            #pragma unroll
            for (int i = 0; i < NR5; ++i)
                ov4[i] = *reinterpret_cast<const float4*>(&obuf[(rbase+i)*28 + d0]);
            float w4[3][4];
            #pragma unroll
            for (int j = 0; j < 3; ++j) {
                const int c = tc + 32*j;
                #pragma unroll
                for (int kk = 0; kk < 4; ++kk)
                    w4[j][kk] = wo[(HD_*h + d0 + kk)*D_ + c];
            }
            #pragma unroll
            for (int j = 0; j < 3; ++j)
                #pragma unroll
                for (int i = 0; i < NR5; ++i)
                    ao[j][i] += ov4[i].x*w4[j][0] + ov4[i].y*w4[j][1]
                              + ov4[i].z*w4[j][2] + ov4[i].w*w4[j][3];
        }
        if (h < NH_-1) stage(h+1);      // writes qh/khT/vhT: disjoint from obuf reads
        __syncthreads();    // A(h+1): staged data visible before next scores
    }

    // ---- epilogue: attended -> LDS, imp softmax, node, LN ----
    #pragma unroll
    for (int j = 0; j < 3; ++j) {
        const int c = tc + 32*j;
        #pragma unroll
        for (int i = 0; i < NR5; ++i) ats[(rbase+i)*100 + c] = ao[j][i];
    }
    __syncthreads();

    if (tid < P_) {                         // row mean over D
        const float* ar = ats + tid*100;
        float s = 0.f;
        for (int d = 0; d < D_; ++d) s += ar[d];
        rr[tid] = s*(1.0f/D_);
    }
    __syncthreads();
    if (tid < 64) {                         // imp = softmax over P (wave 0)
        const float a0 = rr[tid];
        const float a1 = (tid < 8) ? rr[64+tid] : -3.0e38f;
        float mx = fmaxf(a0, a1);
        #pragma unroll
        for (int s = 1; s < 64; s <<= 1) mx = fmaxf(mx, __shfl_xor(mx, s));
        const float e0 = expf(a0-mx);
        const float e1 = (tid < 8) ? expf(a1-mx) : 0.f;
        float sm = e0 + e1;
        #pragma unroll
        for (int s = 1; s < 64; s <<= 1) sm += __shfl_xor(sm, s);
        const float inv = 1.0f/sm;
        rr[tid] = e0*inv;
        if (tid < 8) rr[64+tid] = e1*inv;
    }
    __syncthreads();
    if (tid < D_) {
        float s = 0.f;
        for (int i = 0; i < P_; ++i) s += ats[i*100+tid]*rr[i];
        nb[tid] = s + mpr;
    }
    __syncthreads();
    if (tid < 64) {                         // LN stats (wave 0)
        const float x0 = nb[tid];
        const float x1 = (tid < 32) ? nb[64+tid] : 0.f;
        float sm = x0 + x1;
        float sq = x0*x0 + x1*x1;
        #pragma unroll
        for (int s = 1; s < 64; s <<= 1) { sm += __shfl_xor(sm, s); sq += __shfl_xor(sq, s); }
        if (tid == 0) {
            const float m = sm*(1.0f/D_);
            const float v = sq*(1.0f/D_) - m*m;
            st2[0] = m; st2[1] = rsqrtf(v + 1e-5f);
        }
    }
    __syncthreads();
    if (tid < D_) {
        const float y = (nb[tid]-st2[0])*st2[1]*tng[tid] + tnb[tid];
        node_out[(size_t)bn*D_+tid] = y;
    }
}

// ---------------------------------------------------------------------------
// Kernel 2: h1 = gelu(LN(node @ de_w1 + b1))
// ---------------------------------------------------------------------------
__global__ __launch_bounds__(128) void enc1_kernel(
    const float* __restrict__ node, const float* __restrict__ w1, const float* __restrict__ b1,
    const float* __restrict__ g1, const float* __restrict__ be1, float* __restrict__ h1)
{
    __shared__ float nr[D_];
    __shared__ float buf[128];
    __shared__ float st2[2];
    const int tid = threadIdx.x; const int bn = blockIdx.x;
    if (tid < D_) nr[tid] = node[(size_t)bn*D_+tid];
    __syncthreads();
    float s = b1[tid];
    for (int c = 0; c < D_; ++c) s += nr[c]*w1[c*128+tid];
    buf[tid] = s;
    __syncthreads();
    if (tid == 0) {
        float m=0.f; for(int d=0;d<128;++d) m+=buf[d]; m *= (1.0f/128.0f);
        float v=0.f; for(int d=0;d<128;++d){ float df=buf[d]-m; v+=df*df; } v *= (1.0f/128.0f);
        st2[0]=m; st2[1]=rsqrtf(v+1e-5f);
    }
    __syncthreads();
    float y = (buf[tid]-st2[0])*st2[1]*g1[tid] + be1[tid];
    h1[(size_t)bn*128+tid] = gelu_f(y);
}

// ---------------------------------------------------------------------------
// Kernel 3: dyn = LN(h1 @ de_w2 + b2)
// ---------------------------------------------------------------------------
__global__ __launch_bounds__(64) void enc2_kernel(
    const float* __restrict__ h1, const float* __restrict__ w2, const float* __restrict__ b2,
    const float* __restrict__ g2, const float* __restrict__ be2, float* __restrict__ dyn)
{
    __shared__ float hr[128];
    __shared__ float buf[ND_];
    __shared__ float st2[2];
    const int tid = threadIdx.x; const int bn = blockIdx.x;
    hr[tid] = h1[(size_t)bn*128+tid];
    hr[tid+64] = h1[(size_t)bn*128+64+tid];
    __syncthreads();
    float s = b2[tid];
    for (int c = 0; c < 128; ++c) s += hr[c]*w2[c*ND_+tid];
    buf[tid] = s;
    __syncthreads();
    if (tid == 0) {
        float m=0.f; for(int d=0;d<ND_;++d) m+=buf[d]; m *= (1.0f/ND_);
        float v=0.f; for(int d=0;d<ND_;++d){ float df=buf[d]-m; v+=df*df; } v *= (1.0f/ND_);
        st2[0]=m; st2[1]=rsqrtf(v+1e-5f);
    }
    __syncthreads();
    dyn[(size_t)bn*ND_+tid] = (buf[tid]-st2[0])*st2[1]*g2[tid] + be2[tid];
}

// ---------------------------------------------------------------------------
// Kernel 4: one GNN layer (one block per (b,n) row)
// ---------------------------------------------------------------------------
__global__ __launch_bounds__(256) void gnn_kernel(
    const float* __restrict__ din, float* __restrict__ dout,
    const float* __restrict__ gw, const float* __restrict__ gb,
    const float* __restrict__ gg, const float* __restrict__ gbe, int layer)
{
    __shared__ float dq[ND_];
    __shared__ float prob[N_];
    __shared__ float red[256];
    __shared__ float aggp[4*ND_];
    __shared__ float buf[ND_];
    __shared__ float st2[2];
    const int tid = threadIdx.x; const int bn = blockIdx.x;
    const int b = bn / N_;
    const float* base = din + (size_t)b*N_*ND_;
    if (tid < ND_) dq[tid] = din[(size_t)bn*ND_+tid];
    __syncthreads();

    float lmax = -1e30f;
    for (int m = tid; m < N_; m += 256) {
        const float* rm = base + (size_t)m*ND_;
        float s = 0.f;
        for (int c = 0; c < ND_; ++c) s += dq[c]*rm[c];
        s *= 5.0f;                              // /0.2
        prob[m] = s;
        lmax = fmaxf(lmax, s);
    }
    red[tid]=lmax; __syncthreads();
    for (int st=128; st>0; st>>=1){ if(tid<st) red[tid]=fmaxf(red[tid],red[tid+st]); __syncthreads(); }
    const float mx = red[0]; __syncthreads();
    float lsum = 0.f;
    for (int m=tid; m<N_; m+=256){ float ev=expf(prob[m]-mx); prob[m]=ev; lsum+=ev; }
    red[tid]=lsum; __syncthreads();
    for (int st=128; st>0; st>>=1){ if(tid<st) red[tid]+=red[tid+st]; __syncthreads(); }
    const float inv = 1.0f/red[0]; __syncthreads();
    for (int m=tid; m<N_; m+=256) prob[m]*=inv;
    __syncthreads();

    {   // agg = sim @ dyn
        const int part = tid >> 6, d = tid & 63;
        float s = 0.f;
        for (int m = part; m < N_; m += 4) s += prob[m]*base[(size_t)m*ND_+d];
        aggp[part*ND_+d] = s;
    }
    __syncthreads();
    if (tid < ND_)
        aggp[tid] = aggp[tid]+aggp[ND_+tid]+aggp[2*ND_+tid]+aggp[3*ND_+tid];
    __syncthreads();
    if (tid < ND_) {
        float t = gb[layer*ND_+tid];
        for (int c = 0; c < ND_; ++c) t += aggp[c]*gw[(layer*ND_+c)*ND_+tid];
        buf[tid] = t;
    }
    __syncthreads();
    if (tid == 0) {
        float m=0.f; for(int d=0;d<ND_;++d) m+=buf[d]; m *= (1.0f/ND_);
        float v=0.f; for(int d=0;d<ND_;++d){ float df=buf[d]-m; v+=df*df; } v *= (1.0f/ND_);
        st2[0]=m; st2[1]=rsqrtf(v+1e-5f);
    }
    __syncthreads();
    if (tid < ND_) {
        float y = (buf[tid]-st2[0])*st2[1]*gg[layer*ND_+tid] + gbe[layer*ND_+tid];
        dout[(size_t)bn*ND_+tid] = gelu_f(y) + dq[tid];
    }
}

// ---------------------------------------------------------------------------
// Wave-per-row softmax + top-k + renormalize + store. No __syncthreads.
// lv[j] = relu'd, temperature-scaled logits at positions m = lane + 64*j.
// Tie-break: max value, lowest index (matches lax.top_k stability).
// ---------------------------------------------------------------------------
__device__ __forceinline__ void wave_softmax_topk_store(
    float lv[RPW_], int lane, float* __restrict__ outrow)
{
    float mx = 0.f;                     // logits >= 0 (post-relu), 0 is a valid floor
    #pragma unroll
    for (int j=0;j<RPW_;++j) mx = fmaxf(mx, lv[j]);
    #pragma unroll
    for (int s=1;s<64;s<<=1) mx = fmaxf(mx, __shfl_xor(mx, s));
    float sm = 0.f;
    #pragma unroll
    for (int j=0;j<RPW_;++j) {
        const int m = lane + 64*j;
        const float e = (m < N_) ? expf(lv[j]-mx) : 0.f;
        lv[j] = e; sm += e;
    }
    #pragma unroll
    for (int s=1;s<64;s<<=1) sm += __shfl_xor(sm, s);
    const float inv = 1.0f/sm;
    #pragma unroll
    for (int j=0;j<RPW_;++j) lv[j] *= inv;

    unsigned sel = 0u;
    float ksum = 0.f;
    for (int it = 0; it < K_; ++it) {
        float bv = -1.f; int bm = 0x7fffffff;
        #pragma unroll
        for (int j=0;j<RPW_;++j) {
            const int m = lane + 64*j;
            if (m < N_ && !((sel>>j)&1u) && lv[j] > bv) { bv = lv[j]; bm = m; }
        }
        #pragma unroll
        for (int s=1;s<64;s<<=1) {
            const float ov = __shfl_xor(bv, s);
            const int   om = __shfl_xor(bm, s);
            if (ov > bv || (ov == bv && om < bm)) { bv = ov; bm = om; }
        }
        ksum += bv;
        if ((bm & 63) == lane) sel |= 1u << (bm >> 6);
    }
    const float dn = 1.0f/(ksum + 1e-8f);
    #pragma unroll
    for (int j=0;j<RPW_;++j) {
        const int m = lane + 64*j;
        if (m < N_) outrow[m] = ((sel>>j)&1u) ? lv[j]*dn : 0.f;
    }
}

// ---------------------------------------------------------------------------
// Kernel 5: static adjacency — one WAVE per (h,n) row; 4 rows per block
// ---------------------------------------------------------------------------
__global__ __launch_bounds__(256) void static_adj_kernel(
    const float* __restrict__ le1, const float* __restrict__ le2,
    const float* __restrict__ ge1, const float* __restrict__ ge2,
    const float* __restrict__ temp, float* __restrict__ outs)
{
    __shared__ float e1l[4][ND_];
    const int tid = threadIdx.x;
    const int wv = tid >> 6, lane = tid & 63;
    const int r = blockIdx.x*4 + wv;        // r = h*N_ + n, grid = H_*N_/4
    const int h = r / N_, n = r % N_;
    if (h < 2) { if (lane < 32) e1l[wv][lane] = le1[(h*N_+n)*32+lane]; }
    else       { e1l[wv][lane] = ge1[((h-2)*N_+n)*64+lane]; }
    __syncthreads();
    const float t = temp[h];
    const float tl = (h < 2) ? fminf(fmaxf(t*2.0f,0.1f),5.0f) : fminf(fmaxf(t*0.5f,0.1f),2.0f);
    const float invt = 1.0f/tl;
    float lv[RPW_];
    #pragma unroll
    for (int j=0;j<RPW_;++j) lv[j] = 0.f;
    if (h < 2) {
        for (int c = 0; c < 32; ++c) {
            const float dc = e1l[wv][c];
            const float* sr = le2 + (size_t)(h*32+c)*N_;
            #pragma unroll
            for (int j=0;j<RPW_;++j) {
                const int m = lane + 64*j;
                if (m < N_) lv[j] += dc*sr[m];
            }
        }
    } else {
        for (int c = 0; c < 64; ++c) {
            const float dc = e1l[wv][c];
            const float* sr = ge2 + (size_t)((h-2)*64+c)*N_;
            #pragma unroll
            for (int j=0;j<RPW_;++j) {
                const int m = lane + 64*j;
                if (m < N_) lv[j] += dc*sr[m];
            }
        }
    }
    #pragma unroll
    for (int j=0;j<RPW_;++j) lv[j] = fmaxf(lv[j],0.f)*invt;
    wave_softmax_topk_store(lv, lane, outs + (size_t)r*N_);
}

// ---------------------------------------------------------------------------
// Kernel 6: dynamic adjacency — one WAVE per (b,h,n) row; 4 rows per block
// ---------------------------------------------------------------------------
__global__ __launch_bounds__(256) void dyn_adj_kernel(
    const float* __restrict__ dyn, const float* __restrict__ se2,
    const float* __restrict__ temp, float* __restrict__ outd)
{
    __shared__ float dql[4][ND_];
    const int tid = threadIdx.x;
    const int wv = tid >> 6, lane = tid & 63;
    const int r = blockIdx.x*4 + wv;        // grid = B_*H_*N_/4 = 5728
    const int b = r / (H_*N_);
    const int rem = r % (H_*N_);
    const int h = rem / N_, n = rem % N_;
    dql[wv][lane] = dyn[((size_t)(b*N_+n))*ND_ + lane];
    __syncthreads();
    const float invt = 1.0f/fminf(fmaxf(temp[h],0.1f),2.0f);
    float lv[RPW_];
    #pragma unroll
    for (int j=0;j<RPW_;++j) lv[j] = 0.f;
    const float* sb = se2 + (size_t)h*ND_*N_;
    for (int c = 0; c < ND_; ++c) {
        const float dc = dql[wv][c];
        const float* sr = sb + (size_t)c*N_;
        #pragma unroll
        for (int j=0;j<RPW_;++j) {
            const int m = lane + 64*j;
            if (m < N_) lv[j] += dc*sr[m];
        }
    }
    #pragma unroll
    for (int j=0;j<RPW_;++j) lv[j] = fmaxf(lv[j],0.f)*invt;
    wave_softmax_topk_store(lv, lane, outd + ((size_t)(b*H_+h)*N_+n)*(size_t)N_);
}

// ---------------------------------------------------------------------------
// Kernel 7: fusion gate  w = sigmoid(node_f @ gf_w + gf_b)
// ---------------------------------------------------------------------------
__global__ __launch_bounds__(256) void fw_kernel(
    const float* __restrict__ meanpr, const float* __restrict__ gfw,
    const float* __restrict__ gfb, float* __restrict__ wf)
{
    const int gid = blockIdx.x*256 + threadIdx.x;
    if (gid >= BN_*H_) return;
    const int bn = gid >> 2, h = gid & 3;
    float s = gfb[h];
    const float* mp = meanpr + (size_t)bn*D_;
    for (int c=0;c<D_;++c) s += mp[c]*gfw[c*H_+h];
    wf[gid] = sigm_f(s);
}

// ---------------------------------------------------------------------------
// Kernel 8: fusion + edge-encoder MLP + final (one thread per (b,n,m))
// ---------------------------------------------------------------------------
__global__ __launch_bounds__(256) void edge_kernel(
    const float* __restrict__ staticf, const float* __restrict__ dynf,
    const float* __restrict__ wf,
    const float* __restrict__ ew1, const float* __restrict__ eb1,
    const float* __restrict__ eg,  const float* __restrict__ ebe,
    const float* __restrict__ ew2, const float* __restrict__ eb2,
    const float* __restrict__ ew3, const float* __restrict__ eb3,
    float* __restrict__ outf)
{
    __shared__ float w1s[64], w2s[128], b1s[16], gs[16], bes[16], b2s[8], w3s[8];
    __shared__ float b3v;
    const int tid = threadIdx.x;
    if (tid < 64)                 w1s[tid]     = ew1[tid];
    else if (tid < 192)           w2s[tid-64]  = ew2[tid-64];
    else if (tid < 208)           b1s[tid-192] = eb1[tid-192];
    else if (tid < 224)           gs[tid-208]  = eg[tid-208];
    else if (tid < 240)           bes[tid-224] = ebe[tid-224];
    else if (tid < 248)           b2s[tid-240] = eb2[tid-240];
    else                          w3s[tid-248] = ew3[tid-248];
    if (tid == 0) b3v = eb3[0];
    __syncthreads();

    const size_t gid = (size_t)blockIdx.x*256 + tid;
    if (gid >= (size_t)B_*NN_) return;
    const int m = (int)(gid % N_);
    const size_t t1 = gid / N_;
    const int n = (int)(t1 % N_);
    const int b = (int)(t1 / N_);

    const float* wrow = wf + ((size_t)(b*N_+n))*4;
    float mh[4]; float msum = 0.f;
    #pragma unroll
    for (int h=0; h<4; ++h) {
        float w  = wrow[h];
        float st = staticf[((size_t)(h*N_+n))*N_ + m];
        float da = dynf[(((size_t)(b*4+h))*N_+n)*(size_t)N_ + m];
        float f = (1.0f-w)*st + w*da;
        mh[h] = f; msum += f;
    }
    float e16[16]; float mean = 0.f;
    #pragma unroll
    for (int j=0;j<16;++j) {
        float s = b1s[j];
        #pragma unroll
        for (int h=0;h<4;++h) s += mh[h]*w1s[h*16+j];
        e16[j] = s; mean += s;
    }
    mean *= (1.0f/16.0f);
    float var = 0.f;
    #pragma unroll
    for (int j=0;j<16;++j){ float df=e16[j]-mean; var += df*df; }
    var *= (1.0f/16.0f);
    const float rinv = rsqrtf(var + 1e-5f);
    #pragma unroll
    for (int j=0;j<16;++j) e16[j] = gelu_f((e16[j]-mean)*rinv*gs[j] + bes[j]);
    float e8[8];
    #pragma unroll
    for (int o=0;o<8;++o) {
        float s = b2s[o];
        #pragma unroll
        for (int j=0;j<16;++j) s += e16[j]*w2s[j*8+o];
        e8[o] = gelu_f(s);
    }
    float e = b3v;
    #pragma unroll
    for (int o=0;o<8;++o) e += e8[o]*w3s[o];
    outf[gid] = sigm_f(e) * (msum*0.25f);
}

// ---------------------------------------------------------------------------
extern "C" void kernel_launch(void* const* d_in, const int* in_sizes, int n_in,
                              void* d_out, int out_size, void* d_ws, size_t ws_size,
                              hipStream_t stream)
{
    const float* patch = (const float*)d_in[0];
    const float* le1   = (const float*)d_in[1];
    const float* le2   = (const float*)d_in[2];
    const float* ge1   = (const float*)d_in[3];
    const float* ge2   = (const float*)d_in[4];
    const float* se2   = (const float*)d_in[5];
    const float* temp  = (const float*)d_in[6];
    const float* pos   = (const float*)d_in[7];
    const float* wq    = (const float*)d_in[8];
    const float* bq    = (const float*)d_in[9];
    const float* wk    = (const float*)d_in[10];
    const float* bk    = (const float*)d_in[11];
    const float* wv    = (const float*)d_in[12];
    const float* bv    = (const float*)d_in[13];
    const float* wo    = (const float*)d_in[14];
    const float* bo    = (const float*)d_in[15];
    const float* tng   = (const float*)d_in[16];
    const float* tnb   = (const float*)d_in[17];
    const float* dw1   = (const float*)d_in[18];
    const float* db1   = (const float*)d_in[19];
    const float* dg1   = (const float*)d_in[20];
    const float* dbe1  = (const float*)d_in[21];
    const float* dw2   = (const float*)d_in[22];
    const float* db2   = (const float*)d_in[23];
    const float* dg2   = (const float*)d_in[24];
    const float* dbe2  = (const float*)d_in[25];
    const float* gw    = (const float*)d_in[26];
    const float* gb    = (const float*)d_in[27];
    const float* gg    = (const float*)d_in[28];
    const float* gbe   = (const float*)d_in[29];
    const float* gfw   = (const float*)d_in[30];
    const float* gfb   = (const float*)d_in[31];
    const float* ew1   = (const float*)d_in[32];
    const float* eb1   = (const float*)d_in[33];
    const float* eg    = (const float*)d_in[34];
    const float* ebe   = (const float*)d_in[35];
    const float* ew2   = (const float*)d_in[36];
    const float* eb2   = (const float*)d_in[37];
    const float* ew3   = (const float*)d_in[38];
    const float* eb3   = (const float*)d_in[39];
    (void)in_sizes; (void)n_in; (void)out_size; (void)ws_size;

    // workspace layout (with aliasing of dead buffers): BN*384 floats = 8.8 MB
    float* ws      = (float*)d_ws;
    float* meanpr  = ws;                        // BN*96, live until fw_kernel
    float* node    = meanpr + (size_t)BN_*D_;   // BN*96; dead after enc1 -> reused as dyn1
    float* h1      = node   + (size_t)BN_*D_;   // BN*128; dead after enc2 -> reused as wfuse
    float* dyn0    = h1     + (size_t)BN_*128;  // BN*64
    float* dyn1    = node;                      // alias (gnn layer0 output)
    float* wfuse   = h1;                        // alias (BN*4)

    float* out        = (float*)d_out;
    float* out_final  = out;
    float* out_static = out + (size_t)B_*NN_;
    float* out_dyn    = out_static + (size_t)H_*NN_;

    attn_kernel<<<BN_, 512, 0, stream>>>(patch,pos,wq,bq,wk,bk,wv,bv,wo,bo,tng,tnb,node,meanpr);
    enc1_kernel<<<BN_, 128, 0, stream>>>(node,dw1,db1,dg1,dbe1,h1);
    enc2_kernel<<<BN_, 64,  0, stream>>>(h1,dw2,db2,dg2,dbe2,dyn0);
    gnn_kernel<<<BN_, 256, 0, stream>>>(dyn0,dyn1,gw,gb,gg,gbe,0);
    gnn_kernel<<<BN_, 256, 0, stream>>>(dyn1,dyn0,gw,gb,gg,gbe,1);
    static_adj_kernel<<<H_*N_/4, 256, 0, stream>>>(le1,le2,ge1,ge2,temp,out_static);
    dyn_adj_kernel<<<B_*H_*N_/4, 256, 0, stream>>>(dyn0,se2,temp,out_dyn);
    fw_kernel<<<(BN_*H_+255)/256, 256, 0, stream>>>(meanpr,gfw,gfb,wfuse);
    edge_kernel<<<((size_t)B_*NN_+255)/256, 256, 0, stream>>>(
        out_static,out_dyn,wfuse,ew1,eb1,eg,ebe,ew2,eb2,ew3,eb3,out_final);
}

// Round 2
// 4351.841 us; speedup vs baseline: 2.4378x; 2.4378x over previous
//
#include <hip/hip_runtime.h>
#include <hip/hip_bf16.h>

#define B_ 16
#define N_ 358
#define P_ 72
#define D_ 96
#define ND_ 64
#define H_ 4
#define NH_ 4
#define HD_ 24
#define K_ 10
#define BN_ (B_*N_)     /* 5728 */
#define NN_ (N_*N_)     /* 128164 */
#define RPW_ 6          /* ceil(358/64) elements per lane in wave-per-row kernels */
#define NR5 5           /* rows per 32-lane group in attn (16 groups x 5 = 80 padded rows) */

__device__ __forceinline__ float gelu_f(float x){ return 0.5f*x*(1.0f+erff(x*0.7071067811865476f)); }
__device__ __forceinline__ float sigm_f(float x){ return 1.0f/(1.0f+expf(-x)); }

// ---------------------------------------------------------------------------
// Kernel 1: temporal attention + node embedding (one block per (b,n) sequence)
//
// LAUNCH-BOUNDS SCAR (R1, measured): on this toolchain the 2nd
// __launch_bounds__ arg behaves like CUDA's minBlocksPerMultiprocessor:
// (512,4) -> 4 blocks x 8 waves = 32 waves/CU -> VGPR cap 64 -> 33 GB of
// scratch spill traffic, 10.1 ms (4.4x regression). (256,3)/(384,4) scars
// from the earlier session fit the same semantics. Use (512,2):
// 2 blocks/CU -> 16 waves -> VGPR cap 128 (intended 4 waves/SIMD); under
// the alternative "waves/EU" reading it means 1 block -> cap 256 (benign).
//
// Register budget engineered for the 128 cap:
//  - accumulators aq/ak/av 45 + ao 15 = 60 VGPR live across phases.
//  - phase 1 split into THREE sequential k-loops (one per W matrix) so only
//    one w4[3][4] + xv[5] float4 block is live at a time (peak ~95).
//  - scores phase peak ~115 (sc 15 + qv 20 + kv 12 + 60 acc + misc).
//
// LDS layout: all hot paths ds_read_b128, strides chosen for bank spread:
//  xs/ats [80][100]; qh [80][28]; khT [24][97] (scalar reads, stride-1 over
//  lanes = conflict-free); vhT [24][84] (84%32=20 -> 3-way, was 80 -> 12-way);
//  att [80][76]; obuf [80][28]. Pool 14904 floats = 59.6 KB -> 2 blocks/CU.
// ---------------------------------------------------------------------------
__global__ __launch_bounds__(512, 2) void attn_kernel(
    const float* __restrict__ patch, const float* __restrict__ pos,
    const float* __restrict__ wq, const float* __restrict__ bq,
    const float* __restrict__ wk, const float* __restrict__ bk,
    const float* __restrict__ wv, const float* __restrict__ bv,
    const float* __restrict__ wo, const float* __restrict__ bo,
    const float* __restrict__ tng, const float* __restrict__ tnb,
    float* __restrict__ node_out, float* __restrict__ meanpr_out)
{
    // pool layout (floats):
    //   phase1 : xs  [80][100]              = [0,8000)
    //   heads  : qh  [80][28]  (Q*rs)       = [0,2240)
    //            khT [24][97]  (K^T)        = [2240,4568)
    //            vhT [24][84]  (V^T)        = [4568,6584)
    //            att [80][76]  (P)          = [6584,12664)
    //            obuf[80][28]  (O = P@V)    = [12664,14904)
    //   epilog : ats [80][100] (attended)   = [0,8000)
    __shared__ __align__(16) float pool[14904];
    __shared__ float rr[80];
    __shared__ float nb[D_];
    __shared__ float st2[2];

    float* const xs   = pool;
    float* const qh   = pool;
    float* const khT  = pool + 2240;
    float* const vhT  = pool + 4568;
    float* const att  = pool + 6584;
    float* const obuf = pool + 12664;
    float* const ats  = pool;

    const int tid = threadIdx.x;
    const int tc  = tid & 31;
    const int tr  = tid >> 5;           // 0..15
    const int rbase = tr * NR5;         // 0,5,...,75
    const int bn  = blockIdx.x;
    const float* pr = patch + (size_t)bn * (P_*D_);

    // mean over P of pr (node_f) -- kept in a register by threads tid<96
    float mpr = 0.f;
    if (tid < D_) {
        for (int p = 0; p < P_; ++p) mpr += pr[p*D_+tid];
        mpr *= (1.0f/P_);
        meanpr_out[(size_t)bn*D_ + tid] = mpr;
    }

    // load X = pr + pos into LDS [80][100]; rows 72..79 and cols 96..99 zero
    for (int e = tid; e < 80*100; e += 512) {
        const int row = e / 100, col = e - row*100;
        xs[e] = (row < P_ && col < D_) ? (pr[row*D_+col] + pos[row*D_+col]) : 0.f;
    }
    __syncthreads();

    // ---- phase 1: Q,K,V = X @ W + b; three sequential loops to keep the
    //      per-loop register footprint (xv[5] float4 + one w4[3][4]) small ----
    float aq[3][NR5], ak[3][NR5], av[3][NR5];

#define P1_LOOP(WP, BP, ACC)                                                 \
    {                                                                        \
        _Pragma("unroll")                                                    \
        for (int j = 0; j < 3; ++j) {                                        \
            const float vb = BP[tc + 32*j];                                  \
            _Pragma("unroll")                                                \
            for (int i = 0; i < NR5; ++i) ACC[j][i] = vb;                    \
        }                                                                    \
        for (int k0 = 0; k0 < D_; k0 += 4) {                                 \
            float4 xv[NR5];                                                  \
            _Pragma("unroll")                                                \
            for (int i = 0; i < NR5; ++i)                                    \
                xv[i] = *reinterpret_cast<const float4*>(&xs[(rbase+i)*100 + k0]); \
            float w4[3][4];                                                  \
            _Pragma("unroll")                                                \
            for (int j = 0; j < 3; ++j) {                                    \
                const int c = tc + 32*j;                                     \
                _Pragma("unroll")                                            \
                for (int kk = 0; kk < 4; ++kk)                               \
                    w4[j][kk] = WP[(k0+kk)*D_ + c];                          \
            }                                                                \
            _Pragma("unroll")                                                \
            for (int j = 0; j < 3; ++j)                                      \
                _Pragma("unroll")                                            \
                for (int i = 0; i < NR5; ++i)                                \
                    ACC[j][i] += xv[i].x*w4[j][0] + xv[i].y*w4[j][1]         \
                               + xv[i].z*w4[j][2] + xv[i].w*w4[j][3];        \
        }                                                                    \
    }

    P1_LOOP(wq, bq, aq)
    P1_LOOP(wk, bk, ak)
    P1_LOOP(wv, bv, av)
#undef P1_LOOP

    __syncthreads();        // all xs reads done; pool free for head buffers

    const float rs = 0.20412414523193154f;      // 1/sqrt(24)

    // attended accumulators (output of o @ wo + bo), live across heads
    float ao[3][NR5];
    #pragma unroll
    for (int j = 0; j < 3; ++j) {
        const float vbo = bo[tc + 32*j];
        #pragma unroll
        for (int i = 0; i < NR5; ++i) ao[j][i] = vbo;
    }

    // stage head hh's Q (pre-scaled by rs), K^T, V^T slices from registers
    auto stage = [&](int hh) {
        #pragma unroll
        for (int j = 0; j < 3; ++j) {
            const int c = tc + 32*j;
            const int dl = c - HD_*hh;
            if ((unsigned)dl < (unsigned)HD_) {
                #pragma unroll
                for (int i = 0; i < NR5; ++i) {
                    const int row = rbase + i;
                    qh [row*28 + dl] = aq[j][i] * rs;
                    khT[dl*97 + row] = ak[j][i];
                    vhT[dl*84 + row] = av[j][i];
                }
            }
        }
    };

    stage(0);
    __syncthreads();    // A0: head-0 qh/khT/vhT visible

    for (int h = 0; h < NH_; ++h) {
        // ---- scores S = (Q*rs) K^T, rows rbase..+4, cols jn = tc+32*j ----
        float sc[3][NR5];
        #pragma unroll
        for (int j = 0; j < 3; ++j)
            #pragma unroll
            for (int i = 0; i < NR5; ++i) sc[j][i] = 0.f;
        for (int d0 = 0; d0 < HD_; d0 += 4) {
            float4 qv[NR5];
            #pragma unroll
            for (int i = 0; i < NR5; ++i)
                qv[i] = *reinterpret_cast<const float4*>(&qh[(rbase+i)*28 + d0]);
            float kv[3][4];
            #pragma unroll
            for (int j = 0; j < 3; ++j) {
                const int jn = tc + 32*j;           // <=95 < 97: in-bounds; jn>=72 masked below
                #pragma unroll
                for (int kk = 0; kk < 4; ++kk)
                    kv[j][kk] = khT[(d0+kk)*97 + jn];
            }
            #pragma unroll
            for (int j = 0; j < 3; ++j)
                #pragma unroll
                for (int i = 0; i < NR5; ++i)
                    sc[j][i] += qv[i].x*kv[j][0] + qv[i].y*kv[j][1]
                              + qv[i].z*kv[j][2] + qv[i].w*kv[j][3];
        }

        // ---- in-register row softmax (row owned by one 32-lane group) ----
        #pragma unroll
        for (int i = 0; i < NR5; ++i) {
            float m = fmaxf(sc[0][i], sc[1][i]);
            if (tc < 8) m = fmaxf(m, sc[2][i]);         // jn=64+tc valid iff tc<8
            #pragma unroll
            for (int s = 1; s < 32; s <<= 1) m = fmaxf(m, __shfl_xor(m, s, 32));
            const float e0 = expf(sc[0][i]-m);
            const float e1 = expf(sc[1][i]-m);
            const float e2 = (tc < 8) ? expf(sc[2][i]-m) : 0.f;
            float sm = e0 + e1 + e2;
            #pragma unroll
            for (int s = 1; s < 32; s <<= 1) sm += __shfl_xor(sm, s, 32);
            const float inv = 1.0f/sm;
            const int row = rbase + i;
            att[row*76 + tc]      = e0*inv;
            att[row*76 + tc + 32] = e1*inv;
            if (tc < 8) att[row*76 + tc + 64] = e2*inv;
        }
        __syncthreads();    // B: P visible; qh/khT reads done

        // ---- PV: O[row][tc] = sum_j P[row][j] V[j][tc]  (tc < 24) ----
        if (tc < HD_) {
            float ov[NR5];
            #pragma unroll
            for (int i = 0; i < NR5; ++i) ov[i] = 0.f;
            for (int j0 = 0; j0 < P_; j0 += 4) {
                const float4 vv = *reinterpret_cast<const float4*>(&vhT[tc*84 + j0]);
                #pragma unroll
                for (int i = 0; i < NR5; ++i) {
                    const float4 pa = *reinterpret_cast<const float4*>(&att[(rbase+i)*76 + j0]);
                    ov[i] += pa.x*vv.x + pa.y*vv.y + pa.z*vv.z + pa.w*vv.w;
                }
            }
            #pragma unroll
            for (int i = 0; i < NR5; ++i) obuf[(rbase+i)*28 + tc] = ov[i];
        }
        __syncthreads();    // C: O visible; att/vhT reads done

        // ---- Oproj: attended += O @ wo[24h:24h+24, :]  (+ stage next head) ----
        for (int d0 = 0; d0 < HD_; d0 += 4) {
            float4 ov4[NR5];
            #pragma unroll
            for (int i = 0; i < NR5; ++i)
                ov4[i] = *reinterpret_cast<const float4*>(&obuf[(rbase+i)*28 + d0]);
            float w4[3][4];
            #pragma unroll
            for (int j = 0; j < 3; ++j) {
                const int c = tc + 32*j;
                #pragma unroll
                for (int kk = 0; kk < 4; ++kk)
                    w4[j][kk] = wo[(HD_*h + d0 + kk)*D_ + c];
            }
            #pragma unroll
            for (int j = 0; j < 3; ++j)
                #pragma unroll
                for (int i = 0; i < NR5; ++i)
                    ao[j][i] += ov4[i].x*w4[j][0] + ov4[i].y*w4[j][1]
                              + ov4[i].z*w4[j][2] + ov4[i].w*w4[j][3];
        }
        if (h < NH_-1) stage(h+1);      // writes qh/khT/vhT: disjoint from obuf reads
        __syncthreads();    // A(h+1): staged data visible before next scores
    }

    // ---- epilogue: attended -> LDS, imp softmax, node, LN ----
    #pragma unroll
    for (int j = 0; j < 3; ++j) {
        const int c = tc + 32*j;
        #pragma unroll
        for (int i = 0; i < NR5; ++i) ats[(rbase+i)*100 + c] = ao[j][i];
    }
    __syncthreads();

    if (tid < P_) {                         // row mean over D
        const float* ar = ats + tid*100;
        float s = 0.f;
        for (int d = 0; d < D_; ++d) s += ar[d];
        rr[tid] = s*(1.0f/D_);
    }
    __syncthreads();
    if (tid < 64) {                         // imp = softmax over P (wave 0)
        const float a0 = rr[tid];
        const float a1 = (tid < 8) ? rr[64+tid] : -3.0e38f;
        float mx = fmaxf(a0, a1);
        #pragma unroll
        for (int s = 1; s < 64; s <<= 1) mx = fmaxf(mx, __shfl_xor(mx, s));
        const float e0 = expf(a0-mx);
        const float e1 = (tid < 8) ? expf(a1-mx) : 0.f;
        float sm = e0 + e1;
        #pragma unroll
        for (int s = 1; s < 64; s <<= 1) sm += __shfl_xor(sm, s);
        const float inv = 1.0f/sm;
        rr[tid] = e0*inv;
        if (tid < 8) rr[64+tid] = e1*inv;
    }
    __syncthreads();
    if (tid < D_) {
        float s = 0.f;
        for (int i = 0; i < P_; ++i) s += ats[i*100+tid]*rr[i];
        nb[tid] = s + mpr;
    }
    __syncthreads();
    if (tid < 64) {                         // LN stats (wave 0)
        const float x0 = nb[tid];
        const float x1 = (tid < 32) ? nb[64+tid] : 0.f;
        float sm = x0 + x1;
        float sq = x0*x0 + x1*x1;
        #pragma unroll
        for (int s = 1; s < 64; s <<= 1) { sm += __shfl_xor(sm, s); sq += __shfl_xor(sq, s); }
        if (tid == 0) {
            const float m = sm*(1.0f/D_);
            const float v = sq*(1.0f/D_) - m*m;
            st2[0] = m; st2[1] = rsqrtf(v + 1e-5f);
        }
    }
    __syncthreads();
    if (tid < D_) {
        const float y = (nb[tid]-st2[0])*st2[1]*tng[tid] + tnb[tid];
        node_out[(size_t)bn*D_+tid] = y;
    }
}

// ---------------------------------------------------------------------------
// Kernel 2: h1 = gelu(LN(node @ de_w1 + b1))
// ---------------------------------------------------------------------------
__global__ __launch_bounds__(128) void enc1_kernel(
    const float* __restrict__ node, const float* __restrict__ w1, const float* __restrict__ b1,
    const float* __restrict__ g1, const float* __restrict__ be1, float* __restrict__ h1)
{
    __shared__ float nr[D_];
    __shared__ float buf[128];
    __shared__ float st2[2];
    const int tid = threadIdx.x; const int bn = blockIdx.x;
    if (tid < D_) nr[tid] = node[(size_t)bn*D_+tid];
    __syncthreads();
    float s = b1[tid];
    for (int c = 0; c < D_; ++c) s += nr[c]*w1[c*128+tid];
    buf[tid] = s;
    __syncthreads();
    if (tid == 0) {
        float m=0.f; for(int d=0;d<128;++d) m+=buf[d]; m *= (1.0f/128.0f);
        float v=0.f; for(int d=0;d<128;++d){ float df=buf[d]-m; v+=df*df; } v *= (1.0f/128.0f);
        st2[0]=m; st2[1]=rsqrtf(v+1e-5f);
    }
    __syncthreads();
    float y = (buf[tid]-st2[0])*st2[1]*g1[tid] + be1[tid];
    h1[(size_t)bn*128+tid] = gelu_f(y);
}

// ---------------------------------------------------------------------------
// Kernel 3: dyn = LN(h1 @ de_w2 + b2)
// ---------------------------------------------------------------------------
__global__ __launch_bounds__(64) void enc2_kernel(
    const float* __restrict__ h1, const float* __restrict__ w2, const float* __restrict__ b2,
    const float* __restrict__ g2, const float* __restrict__ be2, float* __restrict__ dyn)
{
    __shared__ float hr[128];
    __shared__ float buf[ND_];
    __shared__ float st2[2];
    const int tid = threadIdx.x; const int bn = blockIdx.x;
    hr[tid] = h1[(size_t)bn*128+tid];
    hr[tid+64] = h1[(size_t)bn*128+64+tid];
    __syncthreads();
    float s = b2[tid];
    for (int c = 0; c < 128; ++c) s += hr[c]*w2[c*ND_+tid];
    buf[tid] = s;
    __syncthreads();
    if (tid == 0) {
        float m=0.f; for(int d=0;d<ND_;++d) m+=buf[d]; m *= (1.0f/ND_);
        float v=0.f; for(int d=0;d<ND_;++d){ float df=buf[d]-m; v+=df*df; } v *= (1.0f/ND_);
        st2[0]=m; st2[1]=rsqrtf(v+1e-5f);
    }
    __syncthreads();
    dyn[(size_t)bn*ND_+tid] = (buf[tid]-st2[0])*st2[1]*g2[tid] + be2[tid];
}

// ---------------------------------------------------------------------------
// Kernel 4: one GNN layer (one block per (b,n) row)
// ---------------------------------------------------------------------------
__global__ __launch_bounds__(256) void gnn_kernel(
    const float* __restrict__ din, float* __restrict__ dout,
    const float* __restrict__ gw, const float* __restrict__ gb,
    const float* __restrict__ gg, const float* __restrict__ gbe, int layer)
{
    __shared__ float dq[ND_];
    __shared__ float prob[N_];
    __shared__ float red[256];
    __shared__ float aggp[4*ND_];
    __shared__ float buf[ND_];
    __shared__ float st2[2];
    const int tid = threadIdx.x; const int bn = blockIdx.x;
    const int b = bn / N_;
    const float* base = din + (size_t)b*N_*ND_;
    if (tid < ND_) dq[tid] = din[(size_t)bn*ND_+tid];
    __syncthreads();

    float lmax = -1e30f;
    for (int m = tid; m < N_; m += 256) {
        const float* rm = base + (size_t)m*ND_;
        float s = 0.f;
        for (int c = 0; c < ND_; ++c) s += dq[c]*rm[c];
        s *= 5.0f;                              // /0.2
        prob[m] = s;
        lmax = fmaxf(lmax, s);
    }
    red[tid]=lmax; __syncthreads();
    for (int st=128; st>0; st>>=1){ if(tid<st) red[tid]=fmaxf(red[tid],red[tid+st]); __syncthreads(); }
    const float mx = red[0]; __syncthreads();
    float lsum = 0.f;
    for (int m=tid; m<N_; m+=256){ float ev=expf(prob[m]-mx); prob[m]=ev; lsum+=ev; }
    red[tid]=lsum; __syncthreads();
    for (int st=128; st>0; st>>=1){ if(tid<st) red[tid]+=red[tid+st]; __syncthreads(); }
    const float inv = 1.0f/red[0]; __syncthreads();
    for (int m=tid; m<N_; m+=256) prob[m]*=inv;
    __syncthreads();

    {   // agg = sim @ dyn
        const int part = tid >> 6, d = tid & 63;
        float s = 0.f;
        for (int m = part; m < N_; m += 4) s += prob[m]*base[(size_t)m*ND_+d];
        aggp[part*ND_+d] = s;
    }
    __syncthreads();
    if (tid < ND_)
        aggp[tid] = aggp[tid]+aggp[ND_+tid]+aggp[2*ND_+tid]+aggp[3*ND_+tid];
    __syncthreads();
    if (tid < ND_) {
        float t = gb[layer*ND_+tid];
        for (int c = 0; c < ND_; ++c) t += aggp[c]*gw[(layer*ND_+c)*ND_+tid];
        buf[tid] = t;
    }
    __syncthreads();
    if (tid == 0) {
        float m=0.f; for(int d=0;d<ND_;++d) m+=buf[d]; m *= (1.0f/ND_);
        float v=0.f; for(int d=0;d<ND_;++d){ float df=buf[d]-m; v+=df*df; } v *= (1.0f/ND_);
        st2[0]=m; st2[1]=rsqrtf(v+1e-5f);
    }
    __syncthreads();
    if (tid < ND_) {
        float y = (buf[tid]-st2[0])*st2[1]*gg[layer*ND_+tid] + gbe[layer*ND_+tid];
        dout[(size_t)bn*ND_+tid] = gelu_f(y) + dq[tid];
    }
}

// ---------------------------------------------------------------------------
// Wave-per-row softmax + top-k + renormalize + store. No __syncthreads.
// lv[j] = relu'd, temperature-scaled logits at positions m = lane + 64*j.
// Tie-break: max value, lowest index (matches lax.top_k stability).
// ---------------------------------------------------------------------------
__device__ __forceinline__ void wave_softmax_topk_store(
    float lv[RPW_], int lane, float* __restrict__ outrow)
{
    float mx = 0.f;                     // logits >= 0 (post-relu), 0 is a valid floor
    #pragma unroll
    for (int j=0;j<RPW_;++j) mx = fmaxf(mx, lv[j]);
    #pragma unroll
    for (int s=1;s<64;s<<=1) mx = fmaxf(mx, __shfl_xor(mx, s));
    float sm = 0.f;
    #pragma unroll
    for (int j=0;j<RPW_;++j) {
        const int m = lane + 64*j;
        const float e = (m < N_) ? expf(lv[j]-mx) : 0.f;
        lv[j] = e; sm += e;
    }
    #pragma unroll
    for (int s=1;s<64;s<<=1) sm += __shfl_xor(sm, s);
    const float inv = 1.0f/sm;
    #pragma unroll
    for (int j=0;j<RPW_;++j) lv[j] *= inv;

    unsigned sel = 0u;
    float ksum = 0.f;
    for (int it = 0; it < K_; ++it) {
        float bv = -1.f; int bm = 0x7fffffff;
        #pragma unroll
        for (int j=0;j<RPW_;++j) {
            const int m = lane + 64*j;
            if (m < N_ && !((sel>>j)&1u) && lv[j] > bv) { bv = lv[j]; bm = m; }
        }
        #pragma unroll
        for (int s=1;s<64;s<<=1) {
            const float ov = __shfl_xor(bv, s);
            const int   om = __shfl_xor(bm, s);
            if (ov > bv || (ov == bv && om < bm)) { bv = ov; bm = om; }
        }
        ksum += bv;
        if ((bm & 63) == lane) sel |= 1u << (bm >> 6);
    }
    const float dn = 1.0f/(ksum + 1e-8f);
    #pragma unroll
    for (int j=0;j<RPW_;++j) {
        const int m = lane + 64*j;
        if (m < N_) outrow[m] = ((sel>>j)&1u) ? lv[j]*dn : 0.f;
    }
}

// ---------------------------------------------------------------------------
// Kernel 5: static adjacency — one WAVE per (h,n) row; 4 rows per block
// ---------------------------------------------------------------------------
__global__ __launch_bounds__(256) void static_adj_kernel(
    const float* __restrict__ le1, const float* __restrict__ le2,
    const float* __restrict__ ge1, const float* __restrict__ ge2,
    const float* __restrict__ temp, float* __restrict__ outs)
{
    __shared__ float e1l[4][ND_];
    const int tid = threadIdx.x;
    const int wv = tid >> 6, lane = tid & 63;
    const int r = blockIdx.x*4 + wv;        // r = h*N_ + n, grid = H_*N_/4
    const int h = r / N_, n = r % N_;
    if (h < 2) { if (lane < 32) e1l[wv][lane] = le1[(h*N_+n)*32+lane]; }
    else       { e1l[wv][lane] = ge1[((h-2)*N_+n)*64+lane]; }
    __syncthreads();
    const float t = temp[h];
    const float tl = (h < 2) ? fminf(fmaxf(t*2.0f,0.1f),5.0f) : fminf(fmaxf(t*0.5f,0.1f),2.0f);
    const float invt = 1.0f/tl;
    float lv[RPW_];
    #pragma unroll
    for (int j=0;j<RPW_;++j) lv[j] = 0.f;
    if (h < 2) {
        for (int c = 0; c < 32; ++c) {
            const float dc = e1l[wv][c];
            const float* sr = le2 + (size_t)(h*32+c)*N_;
            #pragma unroll
            for (int j=0;j<RPW_;++j) {
                const int m = lane + 64*j;
                if (m < N_) lv[j] += dc*sr[m];
            }
        }
    } else {
        for (int c = 0; c < 64; ++c) {
            const float dc = e1l[wv][c];
            const float* sr = ge2 + (size_t)((h-2)*64+c)*N_;
            #pragma unroll
            for (int j=0;j<RPW_;++j) {
                const int m = lane + 64*j;
                if (m < N_) lv[j] += dc*sr[m];
            }
        }
    }
    #pragma unroll
    for (int j=0;j<RPW_;++j) lv[j] = fmaxf(lv[j],0.f)*invt;
    wave_softmax_topk_store(lv, lane, outs + (size_t)r*N_);
}

// ---------------------------------------------------------------------------
// Kernel 6: dynamic adjacency — one WAVE per (b,h,n) row; 4 rows per block
// ---------------------------------------------------------------------------
__global__ __launch_bounds__(256) void dyn_adj_kernel(
    const float* __restrict__ dyn, const float* __restrict__ se2,
    const float* __restrict__ temp, float* __restrict__ outd)
{
    __shared__ float dql[4][ND_];
    const int tid = threadIdx.x;
    const int wv = tid >> 6, lane = tid & 63;
    const int r = blockIdx.x*4 + wv;        // grid = B_*H_*N_/4 = 5728
    const int b = r / (H_*N_);
    const int rem = r % (H_*N_);
    const int h = rem / N_, n = rem % N_;
    dql[wv][lane] = dyn[((size_t)(b*N_+n))*ND_ + lane];
    __syncthreads();
    const float invt = 1.0f/fminf(fmaxf(temp[h],0.1f),2.0f);
    float lv[RPW_];
    #pragma unroll
    for (int j=0;j<RPW_;++j) lv[j] = 0.f;
    const float* sb = se2 + (size_t)h*ND_*N_;
    for (int c = 0; c < ND_; ++c) {
        const float dc = dql[wv][c];
        const float* sr = sb + (size_t)c*N_;
        #pragma unroll
        for (int j=0;j<RPW_;++j) {
            const int m = lane + 64*j;
            if (m < N_) lv[j] += dc*sr[m];
        }
    }
    #pragma unroll
    for (int j=0;j<RPW_;++j) lv[j] = fmaxf(lv[j],0.f)*invt;
    wave_softmax_topk_store(lv, lane, outd + ((size_t)(b*H_+h)*N_+n)*(size_t)N_);
}

// ---------------------------------------------------------------------------
// Kernel 7: fusion gate  w = sigmoid(node_f @ gf_w + gf_b)
// ---------------------------------------------------------------------------
__global__ __launch_bounds__(256) void fw_kernel(
    const float* __restrict__ meanpr, const float* __restrict__ gfw,
    const float* __restrict__ gfb, float* __restrict__ wf)
{
    const int gid = blockIdx.x*256 + threadIdx.x;
    if (gid >= BN_*H_) return;
    const int bn = gid >> 2, h = gid & 3;
    float s = gfb[h];
    const float* mp = meanpr + (size_t)bn*D_;
    for (int c=0;c<D_;++c) s += mp[c]*gfw[c*H_+h];
    wf[gid] = sigm_f(s);
}

// ---------------------------------------------------------------------------
// Kernel 8: fusion + edge-encoder MLP + final (one thread per (b,n,m))
// ---------------------------------------------------------------------------
__global__ __launch_bounds__(256) void edge_kernel(
    const float* __restrict__ staticf, const float* __restrict__ dynf,
    const float* __restrict__ wf,
    const float* __restrict__ ew1, const float* __restrict__ eb1,
    const float* __restrict__ eg,  const float* __restrict__ ebe,
    const float* __restrict__ ew2, const float* __restrict__ eb2,
    const float* __restrict__ ew3, const float* __restrict__ eb3,
    float* __restrict__ outf)
{
    __shared__ float w1s[64], w2s[128], b1s[16], gs[16], bes[16], b2s[8], w3s[8];
    __shared__ float b3v;
    const int tid = threadIdx.x;
    if (tid < 64)                 w1s[tid]     = ew1[tid];
    else if (tid < 192)           w2s[tid-64]  = ew2[tid-64];
    else if (tid < 208)           b1s[tid-192] = eb1[tid-192];
    else if (tid < 224)           gs[tid-208]  = eg[tid-208];
    else if (tid < 240)           bes[tid-224] = ebe[tid-224];
    else if (tid < 248)           b2s[tid-240] = eb2[tid-240];
    else                          w3s[tid-248] = ew3[tid-248];
    if (tid == 0) b3v = eb3[0];
    __syncthreads();

    const size_t gid = (size_t)blockIdx.x*256 + tid;
    if (gid >= (size_t)B_*NN_) return;
    const int m = (int)(gid % N_);
    const size_t t1 = gid / N_;
    const int n = (int)(t1 % N_);
    const int b = (int)(t1 / N_);

    const float* wrow = wf + ((size_t)(b*N_+n))*4;
    float mh[4]; float msum = 0.f;
    #pragma unroll
    for (int h=0; h<4; ++h) {
        float w  = wrow[h];
        float st = staticf[((size_t)(h*N_+n))*N_ + m];
        float da = dynf[(((size_t)(b*4+h))*N_+n)*(size_t)N_ + m];
        float f = (1.0f-w)*st + w*da;
        mh[h] = f; msum += f;
    }
    float e16[16]; float mean = 0.f;
    #pragma unroll
    for (int j=0;j<16;++j) {
        float s = b1s[j];
        #pragma unroll
        for (int h=0;h<4;++h) s += mh[h]*w1s[h*16+j];
        e16[j] = s; mean += s;
    }
    mean *= (1.0f/16.0f);
    float var = 0.f;
    #pragma unroll
    for (int j=0;j<16;++j){ float df=e16[j]-mean; var += df*df; }
    var *= (1.0f/16.0f);
    const float rinv = rsqrtf(var + 1e-5f);
    #pragma unroll
    for (int j=0;j<16;++j) e16[j] = gelu_f((e16[j]-mean)*rinv*gs[j] + bes[j]);
    float e8[8];
    #pragma unroll
    for (int o=0;o<8;++o) {
        float s = b2s[o];
        #pragma unroll
        for (int j=0;j<16;++j) s += e16[j]*w2s[j*8+o];
        e8[o] = gelu_f(s);
    }
    float e = b3v;
    #pragma unroll
    for (int o=0;o<8;++o) e += e8[o]*w3s[o];
    outf[gid] = sigm_f(e) * (msum*0.25f);
}

// ---------------------------------------------------------------------------
extern "C" void kernel_launch(void* const* d_in, const int* in_sizes, int n_in,
                              void* d_out, int out_size, void* d_ws, size_t ws_size,
                              hipStream_t stream)
{
    const float* patch = (const float*)d_in[0];
    const float* le1   = (const float*)d_in[1];
    const float* le2   = (const float*)d_in[2];
    const float* ge1   = (const float*)d_in[3];
    const float* ge2   = (const float*)d_in[4];
    const float* se2   = (const float*)d_in[5];
    const float* temp  = (const float*)d_in[6];
    const float* pos   = (const float*)d_in[7];
    const float* wq    = (const float*)d_in[8];
    const float* bq    = (const float*)d_in[9];
    const float* wk    = (const float*)d_in[10];
    const float* bk    = (const float*)d_in[11];
    const float* wv    = (const float*)d_in[12];
    const float* bv    = (const float*)d_in[13];
    const float* wo    = (const float*)d_in[14];
    const float* bo    = (const float*)d_in[15];
    const float* tng   = (const float*)d_in[16];
    const float* tnb   = (const float*)d_in[17];
    const float* dw1   = (const float*)d_in[18];
    const float* db1   = (const float*)d_in[19];
    const float* dg1   = (const float*)d_in[20];
    const float* dbe1  = (const float*)d_in[21];
    const float* dw2   = (const float*)d_in[22];
    const float* db2   = (const float*)d_in[23];
    const float* dg2   = (const float*)d_in[24];
    const float* dbe2  = (const float*)d_in[25];
    const float* gw    = (const float*)d_in[26];
    const float* gb    = (const float*)d_in[27];
    const float* gg    = (const float*)d_in[28];
    const float* gbe   = (const float*)d_in[29];
    const float* gfw   = (const float*)d_in[30];
    const float* gfb   = (const float*)d_in[31];
    const float* ew1   = (const float*)d_in[32];
    const float* eb1   = (const float*)d_in[33];
    const float* eg    = (const float*)d_in[34];
    const float* ebe   = (const float*)d_in[35];
    const float* ew2   = (const float*)d_in[36];
    const float* eb2   = (const float*)d_in[37];
    const float* ew3   = (const float*)d_in[38];
    const float* eb3   = (const float*)d_in[39];
    (void)in_sizes; (void)n_in; (void)out_size; (void)ws_size;

    // workspace layout (with aliasing of dead buffers): BN*384 floats = 8.8 MB
    float* ws      = (float*)d_ws;
    float* meanpr  = ws;                        // BN*96, live until fw_kernel
    float* node    = meanpr + (size_t)BN_*D_;   // BN*96; dead after enc1 -> reused as dyn1
    float* h1      = node   + (size_t)BN_*D_;   // BN*128; dead after enc2 -> reused as wfuse
    float* dyn0    = h1     + (size_t)BN_*128;  // BN*64
    float* dyn1    = node;                      // alias (gnn layer0 output)
    float* wfuse   = h1;                        // alias (BN*4)

    float* out        = (float*)d_out;
    float* out_final  = out;
    float* out_static = out + (size_t)B_*NN_;
    float* out_dyn    = out_static + (size_t)H_*NN_;

    attn_kernel<<<BN_, 512, 0, stream>>>(patch,pos,wq,bq,wk,bk,wv,bv,wo,bo,tng,tnb,node,meanpr);
    enc1_kernel<<<BN_, 128, 0, stream>>>(node,dw1,db1,dg1,dbe1,h1);
    enc2_kernel<<<BN_, 64,  0, stream>>>(h1,dw2,db2,dg2,dbe2,dyn0);
    gnn_kernel<<<BN_, 256, 0, stream>>>(dyn0,dyn1,gw,gb,gg,gbe,0);
    gnn_kernel<<<BN_, 256, 0, stream>>>(dyn1,dyn0,gw,gb,gg,gbe,1);
    static_adj_kernel<<<H_*N_/4, 256, 0, stream>>>(le1,le2,ge1,ge2,temp,out_static);
    dyn_adj_kernel<<<B_*H_*N_/4, 256, 0, stream>>>(dyn0,se2,temp,out_dyn);
    fw_kernel<<<(BN_*H_+255)/256, 256, 0, stream>>>(meanpr,gfw,gfb,wfuse);
    edge_kernel<<<((size_t)B_*NN_+255)/256, 256, 0, stream>>>(
        out_static,out_dyn,wfuse,ew1,eb1,eg,ebe,ew2,eb2,ew3,eb3,out_final);
}

// Round 3
// 2968.938 us; speedup vs baseline: 3.5733x; 1.4658x over previous
//
#include <hip/hip_runtime.h>
#include <hip/hip_bf16.h>

#define B_ 16
#define N_ 358
#define P_ 72
#define D_ 96
#define ND_ 64
#define H_ 4
#define NH_ 4
#define HD_ 24
#define K_ 10
#define BN_ (B_*N_)     /* 5728 */
#define NN_ (N_*N_)     /* 128164 */
#define RPW_ 6          /* ceil(358/64) elements per lane in wave-per-row kernels */
#define NR5 5           /* rows per 32-lane group in attn (16 groups x 5 = 80 padded rows) */

__device__ __forceinline__ float gelu_f(float x){ return 0.5f*x*(1.0f+erff(x*0.7071067811865476f)); }
__device__ __forceinline__ float sigm_f(float x){ return 1.0f/(1.0f+expf(-x)); }

// ---------------------------------------------------------------------------
// Kernel 1: temporal attention + node embedding (one block per (b,n) sequence)
//
// LAUNCH-BOUNDS SCAR (R1, measured): 2nd __launch_bounds__ arg behaves like
// CUDA minBlocksPerMultiprocessor on this toolchain: (512,4) -> 32 waves/CU
// -> VGPR cap 64 -> 33 GB spill traffic, 10.1 ms. (512,2) -> 16 waves/CU ->
// cap 128 (VGPR_Count=128 confirmed R2).
//
// SPILL SCAR (R2, measured): with cap 128, scores-phase temps at d-chunk 4
// (sc15+qv20+kv12=47 on top of 60 live accs) overflowed by ~5-10 regs ->
// 6.9 GB scratch traffic, 3.8 ms. Fix: d-chunk 2 in scores (temps 31) and
// Oproj (temps 16), plus #pragma unroll 1 on hot loops so the unroller
// can't hoist next-iteration global loads and re-inflate liveness.
// Peak demand now ~103 regs (scores) — fits 128 with margin.
//
// LDS layout: hot paths ds_read_b128/b64, strides for bank spread:
//  xs/ats [80][100]; qh [80][28]; khT [24][97] (lane-consecutive scalar
//  reads = conflict-free); vhT [24][84]; att [80][76] (PV reads are
//  row-broadcast = conflict-free); obuf [80][28].
//  Pool 14904 floats = 59.6 KB -> 2 blocks/CU (LDS-fit), VGPR is binding.
// ---------------------------------------------------------------------------
__global__ __launch_bounds__(512, 2) void attn_kernel(
    const float* __restrict__ patch, const float* __restrict__ pos,
    const float* __restrict__ wq, const float* __restrict__ bq,
    const float* __restrict__ wk, const float* __restrict__ bk,
    const float* __restrict__ wv, const float* __restrict__ bv,
    const float* __restrict__ wo, const float* __restrict__ bo,
    const float* __restrict__ tng, const float* __restrict__ tnb,
    float* __restrict__ node_out, float* __restrict__ meanpr_out)
{
    // pool layout (floats):
    //   phase1 : xs  [80][100]              = [0,8000)
    //   heads  : qh  [80][28]  (Q*rs)       = [0,2240)
    //            khT [24][97]  (K^T)        = [2240,4568)
    //            vhT [24][84]  (V^T)        = [4568,6584)
    //            att [80][76]  (P)          = [6584,12664)
    //            obuf[80][28]  (O = P@V)    = [12664,14904)
    //   epilog : ats [80][100] (attended)   = [0,8000)
    __shared__ __align__(16) float pool[14904];
    __shared__ float rr[80];
    __shared__ float nb[D_];
    __shared__ float st2[2];

    float* const xs   = pool;
    float* const qh   = pool;
    float* const khT  = pool + 2240;
    float* const vhT  = pool + 4568;
    float* const att  = pool + 6584;
    float* const obuf = pool + 12664;
    float* const ats  = pool;

    const int tid = threadIdx.x;
    const int tc  = tid & 31;
    const int tr  = tid >> 5;           // 0..15
    const int rbase = tr * NR5;         // 0,5,...,75
    const int bn  = blockIdx.x;
    const float* pr = patch + (size_t)bn * (P_*D_);

    // mean over P of pr (node_f) -- kept in a register by threads tid<96
    float mpr = 0.f;
    if (tid < D_) {
        #pragma unroll 1
        for (int p = 0; p < P_; ++p) mpr += pr[p*D_+tid];
        mpr *= (1.0f/P_);
        meanpr_out[(size_t)bn*D_ + tid] = mpr;
    }

    // load X = pr + pos into LDS [80][100]; rows 72..79 and cols 96..99 zero
    #pragma unroll 1
    for (int e = tid; e < 80*100; e += 512) {
        const int row = e / 100, col = e - row*100;
        xs[e] = (row < P_ && col < D_) ? (pr[row*D_+col] + pos[row*D_+col]) : 0.f;
    }
    __syncthreads();

    // ---- phase 1: Q,K,V = X @ W + b; three sequential loops to keep the
    //      per-loop register footprint (xv[5] float4 + one w4[3][4]) small ----
    float aq[3][NR5], ak[3][NR5], av[3][NR5];

#define P1_LOOP(WP, BP, ACC)                                                 \
    {                                                                        \
        _Pragma("unroll")                                                    \
        for (int j = 0; j < 3; ++j) {                                        \
            const float vb = BP[tc + 32*j];                                  \
            _Pragma("unroll")                                                \
            for (int i = 0; i < NR5; ++i) ACC[j][i] = vb;                    \
        }                                                                    \
        _Pragma("unroll 1")                                                  \
        for (int k0 = 0; k0 < D_; k0 += 4) {                                 \
            float4 xv[NR5];                                                  \
            _Pragma("unroll")                                                \
            for (int i = 0; i < NR5; ++i)                                    \
                xv[i] = *reinterpret_cast<const float4*>(&xs[(rbase+i)*100 + k0]); \
            float w4[3][4];                                                  \
            _Pragma("unroll")                                                \
            for (int j = 0; j < 3; ++j) {                                    \
                const int c = tc + 32*j;                                     \
                _Pragma("unroll")                                            \
                for (int kk = 0; kk < 4; ++kk)                               \
                    w4[j][kk] = WP[(k0+kk)*D_ + c];                          \
            }                                                                \
            _Pragma("unroll")                                                \
            for (int j = 0; j < 3; ++j)                                      \
                _Pragma("unroll")                                            \
                for (int i = 0; i < NR5; ++i)                                \
                    ACC[j][i] += xv[i].x*w4[j][0] + xv[i].y*w4[j][1]         \
                               + xv[i].z*w4[j][2] + xv[i].w*w4[j][3];        \
        }                                                                    \
    }

    P1_LOOP(wq, bq, aq)
    P1_LOOP(wk, bk, ak)
    P1_LOOP(wv, bv, av)
#undef P1_LOOP

    __syncthreads();        // all xs reads done; pool free for head buffers

    const float rs = 0.20412414523193154f;      // 1/sqrt(24)

    // attended accumulators (output of o @ wo + bo), live across heads
    float ao[3][NR5];
    #pragma unroll
    for (int j = 0; j < 3; ++j) {
        const float vbo = bo[tc + 32*j];
        #pragma unroll
        for (int i = 0; i < NR5; ++i) ao[j][i] = vbo;
    }

    // stage head hh's Q (pre-scaled by rs), K^T, V^T slices from registers
    auto stage = [&](int hh) {
        #pragma unroll
        for (int j = 0; j < 3; ++j) {
            const int c = tc + 32*j;
            const int dl = c - HD_*hh;
            if ((unsigned)dl < (unsigned)HD_) {
                #pragma unroll
                for (int i = 0; i < NR5; ++i) {
                    const int row = rbase + i;
                    qh [row*28 + dl] = aq[j][i] * rs;
                    khT[dl*97 + row] = ak[j][i];
                    vhT[dl*84 + row] = av[j][i];
                }
            }
        }
    };

    stage(0);
    __syncthreads();    // A0: head-0 qh/khT/vhT visible

    #pragma unroll 1
    for (int h = 0; h < NH_; ++h) {
        // ---- scores S = (Q*rs) K^T, rows rbase..+4, cols jn = tc+32*j ----
        // d-chunk 2 (spill scar R2: chunk 4 temps overflowed the 128 cap)
        float sc[3][NR5];
        #pragma unroll
        for (int j = 0; j < 3; ++j)
            #pragma unroll
            for (int i = 0; i < NR5; ++i) sc[j][i] = 0.f;
        #pragma unroll 1
        for (int d0 = 0; d0 < HD_; d0 += 2) {
            float2 qv[NR5];
            #pragma unroll
            for (int i = 0; i < NR5; ++i)
                qv[i] = *reinterpret_cast<const float2*>(&qh[(rbase+i)*28 + d0]);
            float kv[3][2];
            #pragma unroll
            for (int j = 0; j < 3; ++j) {
                const int jn = tc + 32*j;           // <=95 < 97: in-bounds; jn>=72 masked below
                kv[j][0] = khT[(d0+0)*97 + jn];
                kv[j][1] = khT[(d0+1)*97 + jn];
            }
            #pragma unroll
            for (int j = 0; j < 3; ++j)
                #pragma unroll
                for (int i = 0; i < NR5; ++i)
                    sc[j][i] += qv[i].x*kv[j][0] + qv[i].y*kv[j][1];
        }

        // ---- in-register row softmax (row owned by one 32-lane group) ----
        #pragma unroll
        for (int i = 0; i < NR5; ++i) {
            float m = fmaxf(sc[0][i], sc[1][i]);
            if (tc < 8) m = fmaxf(m, sc[2][i]);         // jn=64+tc valid iff tc<8
            #pragma unroll
            for (int s = 1; s < 32; s <<= 1) m = fmaxf(m, __shfl_xor(m, s, 32));
            const float e0 = expf(sc[0][i]-m);
            const float e1 = expf(sc[1][i]-m);
            const float e2 = (tc < 8) ? expf(sc[2][i]-m) : 0.f;
            float sm = e0 + e1 + e2;
            #pragma unroll
            for (int s = 1; s < 32; s <<= 1) sm += __shfl_xor(sm, s, 32);
            const float inv = 1.0f/sm;
            const int row = rbase + i;
            att[row*76 + tc]      = e0*inv;
            att[row*76 + tc + 32] = e1*inv;
            if (tc < 8) att[row*76 + tc + 64] = e2*inv;
        }
        __syncthreads();    // B: P visible; qh/khT reads done

        // ---- PV: O[row][tc] = sum_j P[row][j] V[j][tc]  (tc < 24) ----
        if (tc < HD_) {
            float ov[NR5];
            #pragma unroll
            for (int i = 0; i < NR5; ++i) ov[i] = 0.f;
            #pragma unroll 1
            for (int j0 = 0; j0 < P_; j0 += 4) {
                const float4 vv = *reinterpret_cast<const float4*>(&vhT[tc*84 + j0]);
                #pragma unroll
                for (int i = 0; i < NR5; ++i) {
                    const float4 pa = *reinterpret_cast<const float4*>(&att[(rbase+i)*76 + j0]);
                    ov[i] += pa.x*vv.x + pa.y*vv.y + pa.z*vv.z + pa.w*vv.w;
                }
            }
            #pragma unroll
            for (int i = 0; i < NR5; ++i) obuf[(rbase+i)*28 + tc] = ov[i];
        }
        __syncthreads();    // C: O visible; att/vhT reads done

        // ---- Oproj: attended += O @ wo[24h:24h+24, :]  (+ stage next head) ----
        // d-chunk 2 (same spill-pressure reasoning as scores)
        #pragma unroll 1
        for (int d0 = 0; d0 < HD_; d0 += 2) {
            float2 ov2[NR5];
            #pragma unroll
            for (int i = 0; i < NR5; ++i)
                ov2[i] = *reinterpret_cast<const float2*>(&obuf[(rbase+i)*28 + d0]);
            float w2[3][2];
            #pragma unroll
            for (int j = 0; j < 3; ++j) {
                const int c = tc + 32*j;
                w2[j][0] = wo[(HD_*h + d0 + 0)*D_ + c];
                w2[j][1] = wo[(HD_*h + d0 + 1)*D_ + c];
            }
            #pragma unroll
            for (int j = 0; j < 3; ++j)
                #pragma unroll
                for (int i = 0; i < NR5; ++i)
                    ao[j][i] += ov2[i].x*w2[j][0] + ov2[i].y*w2[j][1];
        }
        if (h < NH_-1) stage(h+1);      // writes qh/khT/vhT: disjoint from obuf reads
        __syncthreads();    // A(h+1): staged data visible before next scores
    }

    // ---- epilogue: attended -> LDS, imp softmax, node, LN ----
    #pragma unroll
    for (int j = 0; j < 3; ++j) {
        const int c = tc + 32*j;
        #pragma unroll
        for (int i = 0; i < NR5; ++i) ats[(rbase+i)*100 + c] = ao[j][i];
    }
    __syncthreads();

    if (tid < P_) {                         // row mean over D
        const float* ar = ats + tid*100;
        float s = 0.f;
        #pragma unroll 1
        for (int d = 0; d < D_; ++d) s += ar[d];
        rr[tid] = s*(1.0f/D_);
    }
    __syncthreads();
    if (tid < 64) {                         // imp = softmax over P (wave 0)
        const float a0 = rr[tid];
        const float a1 = (tid < 8) ? rr[64+tid] : -3.0e38f;
        float mx = fmaxf(a0, a1);
        #pragma unroll
        for (int s = 1; s < 64; s <<= 1) mx = fmaxf(mx, __shfl_xor(mx, s));
        const float e0 = expf(a0-mx);
        const float e1 = (tid < 8) ? expf(a1-mx) : 0.f;
        float sm = e0 + e1;
        #pragma unroll
        for (int s = 1; s < 64; s <<= 1) sm += __shfl_xor(sm, s);
        const float inv = 1.0f/sm;
        rr[tid] = e0*inv;
        if (tid < 8) rr[64+tid] = e1*inv;
    }
    __syncthreads();
    if (tid < D_) {
        float s = 0.f;
        #pragma unroll 1
        for (int i = 0; i < P_; ++i) s += ats[i*100+tid]*rr[i];
        nb[tid] = s + mpr;
    }
    __syncthreads();
    if (tid < 64) {                         // LN stats (wave 0)
        const float x0 = nb[tid];
        const float x1 = (tid < 32) ? nb[64+tid] : 0.f;
        float sm = x0 + x1;
        float sq = x0*x0 + x1*x1;
        #pragma unroll
        for (int s = 1; s < 64; s <<= 1) { sm += __shfl_xor(sm, s); sq += __shfl_xor(sq, s); }
        if (tid == 0) {
            const float m = sm*(1.0f/D_);
            const float v = sq*(1.0f/D_) - m*m;
            st2[0] = m; st2[1] = rsqrtf(v + 1e-5f);
        }
    }
    __syncthreads();
    if (tid < D_) {
        const float y = (nb[tid]-st2[0])*st2[1]*tng[tid] + tnb[tid];
        node_out[(size_t)bn*D_+tid] = y;
    }
}

// ---------------------------------------------------------------------------
// Kernel 2: h1 = gelu(LN(node @ de_w1 + b1))
// ---------------------------------------------------------------------------
__global__ __launch_bounds__(128) void enc1_kernel(
    const float* __restrict__ node, const float* __restrict__ w1, const float* __restrict__ b1,
    const float* __restrict__ g1, const float* __restrict__ be1, float* __restrict__ h1)
{
    __shared__ float nr[D_];
    __shared__ float buf[128];
    __shared__ float st2[2];
    const int tid = threadIdx.x; const int bn = blockIdx.x;
    if (tid < D_) nr[tid] = node[(size_t)bn*D_+tid];
    __syncthreads();
    float s = b1[tid];
    for (int c = 0; c < D_; ++c) s += nr[c]*w1[c*128+tid];
    buf[tid] = s;
    __syncthreads();
    if (tid == 0) {
        float m=0.f; for(int d=0;d<128;++d) m+=buf[d]; m *= (1.0f/128.0f);
        float v=0.f; for(int d=0;d<128;++d){ float df=buf[d]-m; v+=df*df; } v *= (1.0f/128.0f);
        st2[0]=m; st2[1]=rsqrtf(v+1e-5f);
    }
    __syncthreads();
    float y = (buf[tid]-st2[0])*st2[1]*g1[tid] + be1[tid];
    h1[(size_t)bn*128+tid] = gelu_f(y);
}

// ---------------------------------------------------------------------------
// Kernel 3: dyn = LN(h1 @ de_w2 + b2)
// ---------------------------------------------------------------------------
__global__ __launch_bounds__(64) void enc2_kernel(
    const float* __restrict__ h1, const float* __restrict__ w2, const float* __restrict__ b2,
    const float* __restrict__ g2, const float* __restrict__ be2, float* __restrict__ dyn)
{
    __shared__ float hr[128];
    __shared__ float buf[ND_];
    __shared__ float st2[2];
    const int tid = threadIdx.x; const int bn = blockIdx.x;
    hr[tid] = h1[(size_t)bn*128+tid];
    hr[tid+64] = h1[(size_t)bn*128+64+tid];
    __syncthreads();
    float s = b2[tid];
    for (int c = 0; c < 128; ++c) s += hr[c]*w2[c*ND_+tid];
    buf[tid] = s;
    __syncthreads();
    if (tid == 0) {
        float m=0.f; for(int d=0;d<ND_;++d) m+=buf[d]; m *= (1.0f/ND_);
        float v=0.f; for(int d=0;d<ND_;++d){ float df=buf[d]-m; v+=df*df; } v *= (1.0f/ND_);
        st2[0]=m; st2[1]=rsqrtf(v+1e-5f);
    }
    __syncthreads();
    dyn[(size_t)bn*ND_+tid] = (buf[tid]-st2[0])*st2[1]*g2[tid] + be2[tid];
}

// ---------------------------------------------------------------------------
// Kernel 4: one GNN layer (one block per (b,n) row)
// ---------------------------------------------------------------------------
__global__ __launch_bounds__(256) void gnn_kernel(
    const float* __restrict__ din, float* __restrict__ dout,
    const float* __restrict__ gw, const float* __restrict__ gb,
    const float* __restrict__ gg, const float* __restrict__ gbe, int layer)
{
    __shared__ float dq[ND_];
    __shared__ float prob[N_];
    __shared__ float red[256];
    __shared__ float aggp[4*ND_];
    __shared__ float buf[ND_];
    __shared__ float st2[2];
    const int tid = threadIdx.x; const int bn = blockIdx.x;
    const int b = bn / N_;
    const float* base = din + (size_t)b*N_*ND_;
    if (tid < ND_) dq[tid] = din[(size_t)bn*ND_+tid];
    __syncthreads();

    float lmax = -1e30f;
    for (int m = tid; m < N_; m += 256) {
        const float* rm = base + (size_t)m*ND_;
        float s = 0.f;
        for (int c = 0; c < ND_; ++c) s += dq[c]*rm[c];
        s *= 5.0f;                              // /0.2
        prob[m] = s;
        lmax = fmaxf(lmax, s);
    }
    red[tid]=lmax; __syncthreads();
    for (int st=128; st>0; st>>=1){ if(tid<st) red[tid]=fmaxf(red[tid],red[tid+st]); __syncthreads(); }
    const float mx = red[0]; __syncthreads();
    float lsum = 0.f;
    for (int m=tid; m<N_; m+=256){ float ev=expf(prob[m]-mx); prob[m]=ev; lsum+=ev; }
    red[tid]=lsum; __syncthreads();
    for (int st=128; st>0; st>>=1){ if(tid<st) red[tid]+=red[tid+st]; __syncthreads(); }
    const float inv = 1.0f/red[0]; __syncthreads();
    for (int m=tid; m<N_; m+=256) prob[m]*=inv;
    __syncthreads();

    {   // agg = sim @ dyn
        const int part = tid >> 6, d = tid & 63;
        float s = 0.f;
        for (int m = part; m < N_; m += 4) s += prob[m]*base[(size_t)m*ND_+d];
        aggp[part*ND_+d] = s;
    }
    __syncthreads();
    if (tid < ND_)
        aggp[tid] = aggp[tid]+aggp[ND_+tid]+aggp[2*ND_+tid]+aggp[3*ND_+tid];
    __syncthreads();
    if (tid < ND_) {
        float t = gb[layer*ND_+tid];
        for (int c = 0; c < ND_; ++c) t += aggp[c]*gw[(layer*ND_+c)*ND_+tid];
        buf[tid] = t;
    }
    __syncthreads();
    if (tid == 0) {
        float m=0.f; for(int d=0;d<ND_;++d) m+=buf[d]; m *= (1.0f/ND_);
        float v=0.f; for(int d=0;d<ND_;++d){ float df=buf[d]-m; v+=df*df; } v *= (1.0f/ND_);
        st2[0]=m; st2[1]=rsqrtf(v+1e-5f);
    }
    __syncthreads();
    if (tid < ND_) {
        float y = (buf[tid]-st2[0])*st2[1]*gg[layer*ND_+tid] + gbe[layer*ND_+tid];
        dout[(size_t)bn*ND_+tid] = gelu_f(y) + dq[tid];
    }
}

// ---------------------------------------------------------------------------
// Wave-per-row softmax + top-k + renormalize + store. No __syncthreads.
// lv[j] = relu'd, temperature-scaled logits at positions m = lane + 64*j.
// Tie-break: max value, lowest index (matches lax.top_k stability).
// ---------------------------------------------------------------------------
__device__ __forceinline__ void wave_softmax_topk_store(
    float lv[RPW_], int lane, float* __restrict__ outrow)
{
    float mx = 0.f;                     // logits >= 0 (post-relu), 0 is a valid floor
    #pragma unroll
    for (int j=0;j<RPW_;++j) mx = fmaxf(mx, lv[j]);
    #pragma unroll
    for (int s=1;s<64;s<<=1) mx = fmaxf(mx, __shfl_xor(mx, s));
    float sm = 0.f;
    #pragma unroll
    for (int j=0;j<RPW_;++j) {
        const int m = lane + 64*j;
        const float e = (m < N_) ? expf(lv[j]-mx) : 0.f;
        lv[j] = e; sm += e;
    }
    #pragma unroll
    for (int s=1;s<64;s<<=1) sm += __shfl_xor(sm, s);
    const float inv = 1.0f/sm;
    #pragma unroll
    for (int j=0;j<RPW_;++j) lv[j] *= inv;

    unsigned sel = 0u;
    float ksum = 0.f;
    for (int it = 0; it < K_; ++it) {
        float bv = -1.f; int bm = 0x7fffffff;
        #pragma unroll
        for (int j=0;j<RPW_;++j) {
            const int m = lane + 64*j;
            if (m < N_ && !((sel>>j)&1u) && lv[j] > bv) { bv = lv[j]; bm = m; }
        }
        #pragma unroll
        for (int s=1;s<64;s<<=1) {
            const float ov = __shfl_xor(bv, s);
            const int   om = __shfl_xor(bm, s);
            if (ov > bv || (ov == bv && om < bm)) { bv = ov; bm = om; }
        }
        ksum += bv;
        if ((bm & 63) == lane) sel |= 1u << (bm >> 6);
    }
    const float dn = 1.0f/(ksum + 1e-8f);
    #pragma unroll
    for (int j=0;j<RPW_;++j) {
        const int m = lane + 64*j;
        if (m < N_) outrow[m] = ((sel>>j)&1u) ? lv[j]*dn : 0.f;
    }
}

// ---------------------------------------------------------------------------
// Kernel 5: static adjacency — one WAVE per (h,n) row; 4 rows per block
// ---------------------------------------------------------------------------
__global__ __launch_bounds__(256) void static_adj_kernel(
    const float* __restrict__ le1, const float* __restrict__ le2,
    const float* __restrict__ ge1, const float* __restrict__ ge2,
    const float* __restrict__ temp, float* __restrict__ outs)
{
    __shared__ float e1l[4][ND_];
    const int tid = threadIdx.x;
    const int wv = tid >> 6, lane = tid & 63;
    const int r = blockIdx.x*4 + wv;        // r = h*N_ + n, grid = H_*N_/4
    const int h = r / N_, n = r % N_;
    if (h < 2) { if (lane < 32) e1l[wv][lane] = le1[(h*N_+n)*32+lane]; }
    else       { e1l[wv][lane] = ge1[((h-2)*N_+n)*64+lane]; }
    __syncthreads();
    const float t = temp[h];
    const float tl = (h < 2) ? fminf(fmaxf(t*2.0f,0.1f),5.0f) : fminf(fmaxf(t*0.5f,0.1f),2.0f);
    const float invt = 1.0f/tl;
    float lv[RPW_];
    #pragma unroll
    for (int j=0;j<RPW_;++j) lv[j] = 0.f;
    if (h < 2) {
        for (int c = 0; c < 32; ++c) {
            const float dc = e1l[wv][c];
            const float* sr = le2 + (size_t)(h*32+c)*N_;
            #pragma unroll
            for (int j=0;j<RPW_;++j) {
                const int m = lane + 64*j;
                if (m < N_) lv[j] += dc*sr[m];
            }
        }
    } else {
        for (int c = 0; c < 64; ++c) {
            const float dc = e1l[wv][c];
            const float* sr = ge2 + (size_t)((h-2)*64+c)*N_;
            #pragma unroll
            for (int j=0;j<RPW_;++j) {
                const int m = lane + 64*j;
                if (m < N_) lv[j] += dc*sr[m];
            }
        }
    }
    #pragma unroll
    for (int j=0;j<RPW_;++j) lv[j] = fmaxf(lv[j],0.f)*invt;
    wave_softmax_topk_store(lv, lane, outs + (size_t)r*N_);
}

// ---------------------------------------------------------------------------
// Kernel 6: dynamic adjacency — one WAVE per (b,h,n) row; 4 rows per block
// ---------------------------------------------------------------------------
__global__ __launch_bounds__(256) void dyn_adj_kernel(
    const float* __restrict__ dyn, const float* __restrict__ se2,
    const float* __restrict__ temp, float* __restrict__ outd)
{
    __shared__ float dql[4][ND_];
    const int tid = threadIdx.x;
    const int wv = tid >> 6, lane = tid & 63;
    const int r = blockIdx.x*4 + wv;        // grid = B_*H_*N_/4 = 5728
    const int b = r / (H_*N_);
    const int rem = r % (H_*N_);
    const int h = rem / N_, n = rem % N_;
    dql[wv][lane] = dyn[((size_t)(b*N_+n))*ND_ + lane];
    __syncthreads();
    const float invt = 1.0f/fminf(fmaxf(temp[h],0.1f),2.0f);
    float lv[RPW_];
    #pragma unroll
    for (int j=0;j<RPW_;++j) lv[j] = 0.f;
    const float* sb = se2 + (size_t)h*ND_*N_;
    for (int c = 0; c < ND_; ++c) {
        const float dc = dql[wv][c];
        const float* sr = sb + (size_t)c*N_;
        #pragma unroll
        for (int j=0;j<RPW_;++j) {
            const int m = lane + 64*j;
            if (m < N_) lv[j] += dc*sr[m];
        }
    }
    #pragma unroll
    for (int j=0;j<RPW_;++j) lv[j] = fmaxf(lv[j],0.f)*invt;
    wave_softmax_topk_store(lv, lane, outd + ((size_t)(b*H_+h)*N_+n)*(size_t)N_);
}

// ---------------------------------------------------------------------------
// Kernel 7: fusion gate  w = sigmoid(node_f @ gf_w + gf_b)
// ---------------------------------------------------------------------------
__global__ __launch_bounds__(256) void fw_kernel(
    const float* __restrict__ meanpr, const float* __restrict__ gfw,
    const float* __restrict__ gfb, float* __restrict__ wf)
{
    const int gid = blockIdx.x*256 + threadIdx.x;
    if (gid >= BN_*H_) return;
    const int bn = gid >> 2, h = gid & 3;
    float s = gfb[h];
    const float* mp = meanpr + (size_t)bn*D_;
    for (int c=0;c<D_;++c) s += mp[c]*gfw[c*H_+h];
    wf[gid] = sigm_f(s);
}

// ---------------------------------------------------------------------------
// Kernel 8: fusion + edge-encoder MLP + final (one thread per (b,n,m))
// ---------------------------------------------------------------------------
__global__ __launch_bounds__(256) void edge_kernel(
    const float* __restrict__ staticf, const float* __restrict__ dynf,
    const float* __restrict__ wf,
    const float* __restrict__ ew1, const float* __restrict__ eb1,
    const float* __restrict__ eg,  const float* __restrict__ ebe,
    const float* __restrict__ ew2, const float* __restrict__ eb2,
    const float* __restrict__ ew3, const float* __restrict__ eb3,
    float* __restrict__ outf)
{
    __shared__ float w1s[64], w2s[128], b1s[16], gs[16], bes[16], b2s[8], w3s[8];
    __shared__ float b3v;
    const int tid = threadIdx.x;
    if (tid < 64)                 w1s[tid]     = ew1[tid];
    else if (tid < 192)           w2s[tid-64]  = ew2[tid-64];
    else if (tid < 208)           b1s[tid-192] = eb1[tid-192];
    else if (tid < 224)           gs[tid-208]  = eg[tid-208];
    else if (tid < 240)           bes[tid-224] = ebe[tid-224];
    else if (tid < 248)           b2s[tid-240] = eb2[tid-240];
    else                          w3s[tid-248] = ew3[tid-248];
    if (tid == 0) b3v = eb3[0];
    __syncthreads();

    const size_t gid = (size_t)blockIdx.x*256 + tid;
    if (gid >= (size_t)B_*NN_) return;
    const int m = (int)(gid % N_);
    const size_t t1 = gid / N_;
    const int n = (int)(t1 % N_);
    const int b = (int)(t1 / N_);

    const float* wrow = wf + ((size_t)(b*N_+n))*4;
    float mh[4]; float msum = 0.f;
    #pragma unroll
    for (int h=0; h<4; ++h) {
        float w  = wrow[h];
        float st = staticf[((size_t)(h*N_+n))*N_ + m];
        float da = dynf[(((size_t)(b*4+h))*N_+n)*(size_t)N_ + m];
        float f = (1.0f-w)*st + w*da;
        mh[h] = f; msum += f;
    }
    float e16[16]; float mean = 0.f;
    #pragma unroll
    for (int j=0;j<16;++j) {
        float s = b1s[j];
        #pragma unroll
        for (int h=0;h<4;++h) s += mh[h]*w1s[h*16+j];
        e16[j] = s; mean += s;
    }
    mean *= (1.0f/16.0f);
    float var = 0.f;
    #pragma unroll
    for (int j=0;j<16;++j){ float df=e16[j]-mean; var += df*df; }
    var *= (1.0f/16.0f);
    const float rinv = rsqrtf(var + 1e-5f);
    #pragma unroll
    for (int j=0;j<16;++j) e16[j] = gelu_f((e16[j]-mean)*rinv*gs[j] + bes[j]);
    float e8[8];
    #pragma unroll
    for (int o=0;o<8;++o) {
        float s = b2s[o];
        #pragma unroll
        for (int j=0;j<16;++j) s += e16[j]*w2s[j*8+o];
        e8[o] = gelu_f(s);
    }
    float e = b3v;
    #pragma unroll
    for (int o=0;o<8;++o) e += e8[o]*w3s[o];
    outf[gid] = sigm_f(e) * (msum*0.25f);
}

// ---------------------------------------------------------------------------
extern "C" void kernel_launch(void* const* d_in, const int* in_sizes, int n_in,
                              void* d_out, int out_size, void* d_ws, size_t ws_size,
                              hipStream_t stream)
{
    const float* patch = (const float*)d_in[0];
    const float* le1   = (const float*)d_in[1];
    const float* le2   = (const float*)d_in[2];
    const float* ge1   = (const float*)d_in[3];
    const float* ge2   = (const float*)d_in[4];
    const float* se2   = (const float*)d_in[5];
    const float* temp  = (const float*)d_in[6];
    const float* pos   = (const float*)d_in[7];
    const float* wq    = (const float*)d_in[8];
    const float* bq    = (const float*)d_in[9];
    const float* wk    = (const float*)d_in[10];
    const float* bk    = (const float*)d_in[11];
    const float* wv    = (const float*)d_in[12];
    const float* bv    = (const float*)d_in[13];
    const float* wo    = (const float*)d_in[14];
    const float* bo    = (const float*)d_in[15];
    const float* tng   = (const float*)d_in[16];
    const float* tnb   = (const float*)d_in[17];
    const float* dw1   = (const float*)d_in[18];
    const float* db1   = (const float*)d_in[19];
    const float* dg1   = (const float*)d_in[20];
    const float* dbe1  = (const float*)d_in[21];
    const float* dw2   = (const float*)d_in[22];
    const float* db2   = (const float*)d_in[23];
    const float* dg2   = (const float*)d_in[24];
    const float* dbe2  = (const float*)d_in[25];
    const float* gw    = (const float*)d_in[26];
    const float* gb    = (const float*)d_in[27];
    const float* gg    = (const float*)d_in[28];
    const float* gbe   = (const float*)d_in[29];
    const float* gfw   = (const float*)d_in[30];
    const float* gfb   = (const float*)d_in[31];
    const float* ew1   = (const float*)d_in[32];
    const float* eb1   = (const float*)d_in[33];
    const float* eg    = (const float*)d_in[34];
    const float* ebe   = (const float*)d_in[35];
    const float* ew2   = (const float*)d_in[36];
    const float* eb2   = (const float*)d_in[37];
    const float* ew3   = (const float*)d_in[38];
    const float* eb3   = (const float*)d_in[39];
    (void)in_sizes; (void)n_in; (void)out_size; (void)ws_size;

    // workspace layout (with aliasing of dead buffers): BN*384 floats = 8.8 MB
    float* ws      = (float*)d_ws;
    float* meanpr  = ws;                        // BN*96, live until fw_kernel
    float* node    = meanpr + (size_t)BN_*D_;   // BN*96; dead after enc1 -> reused as dyn1
    float* h1      = node   + (size_t)BN_*D_;   // BN*128; dead after enc2 -> reused as wfuse
    float* dyn0    = h1     + (size_t)BN_*128;  // BN*64
    float* dyn1    = node;                      // alias (gnn layer0 output)
    float* wfuse   = h1;                        // alias (BN*4)

    float* out        = (float*)d_out;
    float* out_final  = out;
    float* out_static = out + (size_t)B_*NN_;
    float* out_dyn    = out_static + (size_t)H_*NN_;

    attn_kernel<<<BN_, 512, 0, stream>>>(patch,pos,wq,bq,wk,bk,wv,bv,wo,bo,tng,tnb,node,meanpr);
    enc1_kernel<<<BN_, 128, 0, stream>>>(node,dw1,db1,dg1,dbe1,h1);
    enc2_kernel<<<BN_, 64,  0, stream>>>(h1,dw2,db2,dg2,dbe2,dyn0);
    gnn_kernel<<<BN_, 256, 0, stream>>>(dyn0,dyn1,gw,gb,gg,gbe,0);
    gnn_kernel<<<BN_, 256, 0, stream>>>(dyn1,dyn0,gw,gb,gg,gbe,1);
    static_adj_kernel<<<H_*N_/4, 256, 0, stream>>>(le1,le2,ge1,ge2,temp,out_static);
    dyn_adj_kernel<<<B_*H_*N_/4, 256, 0, stream>>>(dyn0,se2,temp,out_dyn);
    fw_kernel<<<(BN_*H_+255)/256, 256, 0, stream>>>(meanpr,gfw,gfb,wfuse);
    edge_kernel<<<((size_t)B_*NN_+255)/256, 256, 0, stream>>>(
        out_static,out_dyn,wfuse,ew1,eb1,eg,ebe,ew2,eb2,ew3,eb3,out_final);
}